// Round 10
// baseline (204.033 us; speedup 1.0000x reference)
//
#include <hip/hip_runtime.h>
#include <math.h>

// VanillaRNN, Wh is (1,H) => scalar recurrence per batch element:
//   s_{t+1} = G(u_t, s_t),  G(u,s) = bh + sum_j wh_j*tanh(wx_j*u + bx_j + s)
// R10: SINGLE-LAUNCH fusion of R9's validated pipeline (table -> 2-segment
// speculative scan -> 14-node piecewise-cubic combine -> head).
//  - R4/R6/R9 all show ~97-107us fixed cost at 3 launches (~30us/launch gap)
//    vs kernel-sum ~57us -> launches are now the bottleneck, not the scan.
//  - 240 blocks, 83.2KB LDS each -> 1 block/CU (LDS pin), 240<=256 CUs ->
//    all blocks co-resident -> software grid barrier cannot deadlock.
//  - Barriers: agent-scope atomic counters in d_out's last 8 bytes, zeroed by
//    a captured hipMemsetAsync; head overwrites them at the end (softmax
//    floats read as uint >= 2^23 >> 240, so late spinners still exit).
//  - __threadfence (agent fence) around arrive/exit: emits L2 wb/inv on
//    gfx950 -> cross-XCD visibility of table & boundary states.

#define SEQ   512
#define BATCH 4096
#define HID   2048
#define NOUT  10
#define KPL   32
#define NS    560           // s-grid rows over [-10,10]
#define ROWQ  9             // float4s per s-row (8 u-cells + 1 pad)
#define NB    240           // fused grid: 16 seg0 + 14 nodes x 16 seg1

#define S_LOc   (-10.0f)
#define S_H     (20.0f / 559.0f)
#define S_INVH  (559.0f / 20.0f)
#define S_BIAS  (10.0f * S_INVH)
#define NSM1F   559.0f
#define NSM4F   556.0f
#define U_SCALE (8.0f / 14.0f)
#define U_BIAS  4.0f
#define UCMAXF  7.99951f

#define TABLE_FLOATS (NS * ROWQ * 4)       // 20160 floats (d_out scratch)
#define CNT_IDX      40952                 // 2 uint counters in d_out tail
#define WSA_FLOATS   (4096 + 14 * 4096)    // z255 + 14 node bufs (ws)
#define WSB_FLOATS   (4096 + 4 * 4096)
#define DZ14 43.0f                         // 559/13, exact
#define DZ9  69.875f                       // 559/8, exact

__device__ __forceinline__ float fast_exp2(float v) { return __builtin_amdgcn_exp2f(v); }
__device__ __forceinline__ float fast_rcp(float v)  { return __builtin_amdgcn_rcpf(v); }
__device__ __forceinline__ float fast_tanh(float a) {
    const float C = 2.8853900817779268f;  // 2*log2(e)
    return __builtin_fmaf(-2.0f, fast_rcp(fast_exp2(C * a) + 1.0f), 1.0f);
}
__device__ __forceinline__ float wave_sum(float v) {
#pragma unroll
    for (int m = 1; m < 64; m <<= 1) v += __shfl_xor(v, m, 64);
    return v;
}

__device__ __forceinline__ void grid_barrier(unsigned* cnt) {
    __syncthreads();
    if (threadIdx.x == 0) {
        __threadfence();                               // release (L2 writeback)
        __hip_atomic_fetch_add(cnt, 1u, __ATOMIC_ACQ_REL, __HIP_MEMORY_SCOPE_AGENT);
        unsigned v;
        do {
            __builtin_amdgcn_s_sleep(8);
            v = __hip_atomic_load(cnt, __ATOMIC_ACQUIRE, __HIP_MEMORY_SCOPE_AGENT);
        } while (v < (unsigned)NB);
        __threadfence();                               // acquire (L1/L2 invalidate)
    }
    __syncthreads();
}

// piecewise-cubic Lagrange combine over 14 uniform nodes (bufs at nodes+n*4096)
__device__ __forceinline__ float combine14(float z255, const float* nodes, int e) {
    float p = z255 * (1.0f / DZ14);
    int   c = min(max((int)floorf(p) - 1, 0), 10);
    float t = p - (float)c;
    float a0 = t, a1 = t - 1.0f, a2 = t - 2.0f, a3 = t - 3.0f;
    float m01 = a0 * a1, m23 = a2 * a3;
    float w0 = a1 * m23 * (-1.0f / 6.0f), w1 = a0 * m23 * 0.5f;
    float w2 = m01 * a3 * (-0.5f),        w3 = m01 * a2 * (1.0f / 6.0f);
    float y0 = nodes[(size_t)c * 4096 + e];
    float y1 = nodes[(size_t)(c + 1) * 4096 + e];
    float y2 = nodes[(size_t)(c + 2) * 4096 + e];
    float y3 = nodes[(size_t)(c + 3) * 4096 + e];
    return __builtin_fmaf(w0, y0, w1 * y1) + __builtin_fmaf(w2, y2, w3 * y3);
}

// ==================== R10 fused kernel ====================
__global__ __launch_bounds__(256) void k_fused(
    const float* __restrict__ x,  const float* __restrict__ Wx,
    const float* __restrict__ bx, const float* __restrict__ Wh,
    const float* __restrict__ bh, const float* __restrict__ Wy,
    const float* __restrict__ by, float* __restrict__ out,
    float* __restrict__ ws)
{
    __shared__ float4 tabs[5200];                // 83200 B -> pins 1 block/CU
    float* scr = (float*)tabs;                   // phase-A scratch alias
    const int blk = blockIdx.x, tid = threadIdx.x;
    unsigned* cnt = (unsigned*)(out + CNT_IDX);
    float* tab_g = out;                          // table scratch in d_out

    // ---------- Phase A: build coefficient table (rows blk, blk+240, ...) ----------
    {
        const int node = tid & 31, jc = tid >> 5;
        const int cell = node >> 2, nn = node & 3;
        const float xi_n = (nn == 0) ? 0.923879533f : (nn == 1) ? 0.382683432f
                         : (nn == 2) ? -0.382683432f : -0.923879533f;
        const float un = (-7.0f + ((float)cell + 0.5f) * 1.75f) + 0.875f * xi_n;
        for (int r = blk; r < NS; r += NB) {
            const float sn = S_LOc + (float)r * S_H;
            float p = 0.0f;
            const int j0 = jc * 256;
#pragma unroll 4
            for (int j = j0; j < j0 + 256; ++j)
                p += Wh[j] * fast_tanh(__builtin_fmaf(Wx[j], un, bx[j] + sn));
            scr[tid] = p;
            __syncthreads();
            if (tid < 32) {
                float V = bh[0];
#pragma unroll
                for (int c = 0; c < 8; ++c) V += scr[tid + 32 * c];
                scr[256 + tid] = __builtin_fmaf(V, S_INVH, S_BIAS);
            }
            __syncthreads();
            if (tid < 8) {
                const int c = tid;
                float G0 = scr[256 + 4*c], G1 = scr[257 + 4*c], G2 = scr[258 + 4*c], G3 = scr[259 + 4*c];
                float d03 = G0 - G3, d12 = G1 - G2;
                float a0 = 0.25f * (G0 + G1 + G2 + G3);
                float a1 = 0.5f * (0.923879533f * d03 + 0.382683432f * d12);
                float a2 = 0.5f * 0.707106781f * (G0 - G1 - G2 + G3);
                float a3 = 0.5f * (0.382683432f * d03 - 0.923879533f * d12);
                ((float4*)tab_g)[r * ROWQ + c] =
                    make_float4(a0 - a2, a1 - 3.0f * a3, 2.0f * a2, 4.0f * a3);
            } else if (tid == 8) {
                ((float4*)tab_g)[r * ROWQ + 8] = make_float4(0.f, 0.f, 0.f, 0.f);
            }
            __syncthreads();                     // scr reused next row
        }
    }
    grid_barrier(cnt);                            // table globally visible

    // ---------- Phase B: 2-segment speculative scan (R9-validated) ----------
    {
        const float4* src = (const float4*)tab_g;
        for (int i = tid; i < NS * ROWQ; i += 256) tabs[i] = src[i];
        __syncthreads();

        const int seg  = (blk < 16) ? 0 : 1;
        const int node = seg ? (blk - 16) >> 4 : 0;
        const int eb   = seg ? (blk - 16) & 15 : blk;
        const int b    = eb * 256 + tid;
        const int t0     = seg ? 255 : 0;
        const int nsteps = seg ? 256 : 255;

        float z = seg ? (float)node * DZ14
                      : fminf(fmaxf(__builtin_fmaf(bh[0], S_INVH, S_BIAS), 0.0f), NSM1F);

        auto step1 = [&](float u) {
            float uc = fminf(fmaxf(__builtin_fmaf(u, U_SCALE, U_BIAS), 0.0f), UCMAXF);
            float cf = floorf(uc);
            float xi = __builtin_fmaf(2.0f, uc - cf, -1.0f);
            int   ci = (int)cf;
            float zc  = fminf(fmaxf(z, 0.0f), NSM1F);
            float kzf = fminf(fmaxf(floorf(zc) - 1.0f, 0.0f), NSM4F);
            int   kzi = (int)kzf;
            float ts  = zc - kzf;
            float c0 = ts, c1 = ts - 1.0f, c2 = ts - 2.0f, c3 = ts - 3.0f;
            float n01 = c0 * c1, n23 = c2 * c3;
            float ws0 = c1 * n23 * (-1.0f / 6.0f), ws1 = c0 * n23 * 0.5f;
            float ws2 = n01 * c3 * (-0.5f),        ws3 = n01 * c2 * (1.0f / 6.0f);
            const int base = kzi * ROWQ + ci;
            float4 q0 = tabs[base];
            float4 q1 = tabs[base + ROWQ];
            float4 q2 = tabs[base + 2 * ROWQ];
            float4 q3 = tabs[base + 3 * ROWQ];
            float r0 = __builtin_fmaf(__builtin_fmaf(__builtin_fmaf(q0.w, xi, q0.z), xi, q0.y), xi, q0.x);
            float r1 = __builtin_fmaf(__builtin_fmaf(__builtin_fmaf(q1.w, xi, q1.z), xi, q1.y), xi, q1.x);
            float r2 = __builtin_fmaf(__builtin_fmaf(__builtin_fmaf(q2.w, xi, q2.z), xi, q2.y), xi, q2.x);
            float r3 = __builtin_fmaf(__builtin_fmaf(__builtin_fmaf(q3.w, xi, q3.z), xi, q3.y), xi, q3.x);
            z = __builtin_fmaf(ws0, r0, ws1 * r1) + __builtin_fmaf(ws2, r2, ws3 * r3);
        };

        float cur[8], nxt[8];
#pragma unroll
        for (int i = 0; i < 8; ++i)
            cur[i] = x[(size_t)min(t0 + i, SEQ - 1) * BATCH + b];
        const int full = nsteps >> 3, tail = nsteps & 7;
        for (int c = 0; c < full; ++c) {
            const int nb = t0 + (c + 1) * 8;
#pragma unroll
            for (int i = 0; i < 8; ++i)
                nxt[i] = x[(size_t)min(nb + i, SEQ - 1) * BATCH + b];
#pragma unroll
            for (int i = 0; i < 8; ++i) step1(cur[i]);
#pragma unroll
            for (int i = 0; i < 8; ++i) cur[i] = nxt[i];
        }
        for (int i = 0; i < tail; ++i) step1(cur[i]);

        if (seg == 0) ws[b] = z;
        else ws[4096 + (size_t)node * 4096 + b] = z;
    }
    grid_barrier(cnt + 1);                        // boundary states visible

    // ---------- Phase C: combine + head, spread over all 960 waves ----------
    {
        const int lane = tid & 63;
        const int gw   = blk * 4 + (tid >> 6);    // 0..959
        const float C  = 2.8853900817779268f;
        const float L2E = 1.4426950408889634f;
        for (int e = gw; e < BATCH; e += NB * 4) {
            float zz = combine14(ws[e], ws + 4096, e);
            const float s  = __builtin_fmaf(zz, S_H, S_LOc);
            const float u  = x[(size_t)(SEQ - 1) * BATCH + e];
            const float sc = s * C;
            float acc[NOUT];
#pragma unroll
            for (int i = 0; i < NOUT; ++i) acc[i] = 0.0f;
#pragma unroll 4
            for (int k = 0; k < KPL; ++k) {
                const int j = k * 64 + lane;
                float arg = __builtin_fmaf(u, Wx[j] * C, bx[j] * C) + sc;
                float r   = fast_rcp(fast_exp2(arg) + 1.0f);
                float th  = __builtin_fmaf(-2.0f, r, 1.0f);
#pragma unroll
                for (int i = 0; i < NOUT; ++i)
                    acc[i] = __builtin_fmaf(Wy[i * HID + j], th, acc[i]);
            }
#pragma unroll
            for (int i = 0; i < NOUT; ++i) acc[i] = wave_sum(acc[i]) + by[i];
            float m = acc[0];
#pragma unroll
            for (int i = 1; i < NOUT; ++i) m = fmaxf(m, acc[i]);
            float ev[NOUT]; float Z = 0.0f;
#pragma unroll
            for (int i = 0; i < NOUT; ++i) { ev[i] = fast_exp2((acc[i] - m) * L2E); Z += ev[i]; }
            const float rz = fast_rcp(Z);
            if (lane == 0) {
#pragma unroll
                for (int i = 0; i < NOUT; ++i) out[(size_t)e * NOUT + i] = ev[i] * rz;
            }
        }
    }
}

// ==================== fallbacks (validated R0/R9) ====================
__device__ __forceinline__ float combine_eval(float z255, int nn, float dz,
                                              const float* baseA, const float* baseB,
                                              int split, int b) {
    float p = z255 / dz;
    int   c = min(max((int)floorf(p) - 1, 0), nn - 4);
    float t = p - (float)c;
    float a0 = t, a1 = t - 1.0f, a2 = t - 2.0f, a3 = t - 3.0f;
    float m01 = a0 * a1, m23 = a2 * a3;
    float w0 = a1 * m23 * (-1.0f / 6.0f), w1 = a0 * m23 * 0.5f;
    float w2 = m01 * a3 * (-0.5f),        w3 = m01 * a2 * (1.0f / 6.0f);
    float y[4];
#pragma unroll
    for (int i = 0; i < 4; ++i) {
        int n = c + i;
        const float* ptr = (n < split) ? (baseA + (size_t)n * 4096)
                                       : (baseB + (size_t)(n - split) * 4096);
        y[i] = ptr[b];
    }
    return __builtin_fmaf(w0, y[0], w1 * y[1]) + __builtin_fmaf(w2, y[2], w3 * y[3]);
}

__global__ __launch_bounds__(256) void k_coef(const float* __restrict__ Wx, const float* __restrict__ bx,
                                              const float* __restrict__ Wh, const float* __restrict__ bh,
                                              float* __restrict__ tab_g) {
    __shared__ float red[256];
    __shared__ float Gn[32];
    const int k    = blockIdx.x;
    const int node = threadIdx.x & 31, jc = threadIdx.x >> 5;
    const int cell = node >> 2, nn = node & 3;
    const float sn = S_LOc + (float)k * S_H;
    const float xi_n = (nn == 0) ? 0.923879533f : (nn == 1) ? 0.382683432f
                     : (nn == 2) ? -0.382683432f : -0.923879533f;
    const float un = (-7.0f + ((float)cell + 0.5f) * 1.75f) + 0.875f * xi_n;
    float p = 0.0f;
    const int j0 = jc * 256;
#pragma unroll 4
    for (int j = j0; j < j0 + 256; ++j)
        p += Wh[j] * fast_tanh(__builtin_fmaf(Wx[j], un, bx[j] + sn));
    red[threadIdx.x] = p;
    __syncthreads();
    if (threadIdx.x < 32) {
        float V = bh[0];
#pragma unroll
        for (int c = 0; c < 8; ++c) V += red[threadIdx.x + 32 * c];
        Gn[threadIdx.x] = __builtin_fmaf(V, S_INVH, S_BIAS);
    }
    __syncthreads();
    float4* wq = (float4*)tab_g;
    if (threadIdx.x < 8) {
        const int c = threadIdx.x;
        float G0 = Gn[4*c+0], G1 = Gn[4*c+1], G2 = Gn[4*c+2], G3 = Gn[4*c+3];
        float d03 = G0 - G3, d12 = G1 - G2;
        float a0 = 0.25f * (G0 + G1 + G2 + G3);
        float a1 = 0.5f * (0.923879533f * d03 + 0.382683432f * d12);
        float a2 = 0.5f * 0.707106781f * (G0 - G1 - G2 + G3);
        float a3 = 0.5f * (0.382683432f * d03 - 0.923879533f * d12);
        wq[k * ROWQ + c] = make_float4(a0 - a2, a1 - 3.0f * a3, 2.0f * a2, 4.0f * a3);
    } else if (threadIdx.x == 8) {
        wq[k * ROWQ + 8] = make_float4(0.f, 0.f, 0.f, 0.f);
    }
}

__global__ __launch_bounds__(256) void k_scan_seg(const float* __restrict__ x,
                                                  const float* __restrict__ bh,
                                                  const float* __restrict__ tab_g,
                                                  float* __restrict__ z255,
                                                  float* __restrict__ baseA,
                                                  float* __restrict__ baseB,
                                                  int split, float dz) {
    __shared__ float4 tabs[5200];
    {
        const float4* src = (const float4*)tab_g;
        for (int i = threadIdx.x; i < NS * ROWQ; i += 256) tabs[i] = src[i];
    }
    __syncthreads();
    const int blk = blockIdx.x;
    const int seg  = (blk < 16) ? 0 : 1;
    const int node = seg ? (blk - 16) >> 4 : 0;
    const int eb   = seg ? (blk - 16) & 15 : blk;
    const int b    = eb * 256 + threadIdx.x;
    const int t0     = seg ? 255 : 0;
    const int nsteps = seg ? 256 : 255;
    float z = seg ? (float)node * dz
                  : fminf(fmaxf(__builtin_fmaf(bh[0], S_INVH, S_BIAS), 0.0f), NSM1F);
    auto step1 = [&](float u) {
        float uc = fminf(fmaxf(__builtin_fmaf(u, U_SCALE, U_BIAS), 0.0f), UCMAXF);
        float cf = floorf(uc);
        float xi = __builtin_fmaf(2.0f, uc - cf, -1.0f);
        int   ci = (int)cf;
        float zc  = fminf(fmaxf(z, 0.0f), NSM1F);
        float kzf = fminf(fmaxf(floorf(zc) - 1.0f, 0.0f), NSM4F);
        int   kzi = (int)kzf;
        float ts  = zc - kzf;
        float c0 = ts, c1 = ts - 1.0f, c2 = ts - 2.0f, c3 = ts - 3.0f;
        float n01 = c0 * c1, n23 = c2 * c3;
        float ws0 = c1 * n23 * (-1.0f / 6.0f), ws1 = c0 * n23 * 0.5f;
        float ws2 = n01 * c3 * (-0.5f),        ws3 = n01 * c2 * (1.0f / 6.0f);
        const int base = kzi * ROWQ + ci;
        float4 q0 = tabs[base];
        float4 q1 = tabs[base + ROWQ];
        float4 q2 = tabs[base + 2 * ROWQ];
        float4 q3 = tabs[base + 3 * ROWQ];
        float r0 = __builtin_fmaf(__builtin_fmaf(__builtin_fmaf(q0.w, xi, q0.z), xi, q0.y), xi, q0.x);
        float r1 = __builtin_fmaf(__builtin_fmaf(__builtin_fmaf(q1.w, xi, q1.z), xi, q1.y), xi, q1.x);
        float r2 = __builtin_fmaf(__builtin_fmaf(__builtin_fmaf(q2.w, xi, q2.z), xi, q2.y), xi, q2.x);
        float r3 = __builtin_fmaf(__builtin_fmaf(__builtin_fmaf(q3.w, xi, q3.z), xi, q3.y), xi, q3.x);
        z = __builtin_fmaf(ws0, r0, ws1 * r1) + __builtin_fmaf(ws2, r2, ws3 * r3);
    };
    float cur[8], nxt[8];
#pragma unroll
    for (int i = 0; i < 8; ++i)
        cur[i] = x[(size_t)min(t0 + i, SEQ - 1) * BATCH + b];
    const int full = nsteps >> 3, tail = nsteps & 7;
    for (int c = 0; c < full; ++c) {
        const int nb = t0 + (c + 1) * 8;
#pragma unroll
        for (int i = 0; i < 8; ++i)
            nxt[i] = x[(size_t)min(nb + i, SEQ - 1) * BATCH + b];
#pragma unroll
        for (int i = 0; i < 8; ++i) step1(cur[i]);
#pragma unroll
        for (int i = 0; i < 8; ++i) cur[i] = nxt[i];
    }
    for (int i = 0; i < tail; ++i) step1(cur[i]);
    if (seg == 0) z255[b] = z;
    else {
        float* p = (node < split) ? (baseA + (size_t)node * 4096)
                                  : (baseB + (size_t)(node - split) * 4096);
        p[b] = z;
    }
}

__global__ __launch_bounds__(256) void k_combine(const float* __restrict__ baseA,
                                                 const float* __restrict__ baseB,
                                                 int split, int nn, float dz,
                                                 float* __restrict__ zs) {
    const int b = blockIdx.x * 256 + threadIdx.x;
    float zz = combine_eval(zs[b], nn, dz, baseA, baseB, split, b);
    zs[b] = __builtin_fmaf(zz, S_H, S_LOc);
}

__global__ __launch_bounds__(256) void rnn_scan_exact(
    const float* __restrict__ x,  const float* __restrict__ Wx,
    const float* __restrict__ bx, const float* __restrict__ Wh,
    const float* __restrict__ bh, float* __restrict__ s_out)
{
    const int lane = threadIdx.x & 63;
    const int wave = threadIdx.x >> 6;
    const int b    = blockIdx.x * 4 + wave;
    const float C = 2.8853900817779268f;
    float wxs[KPL], bxs[KPL], whn[KPL];
    float swh = 0.0f;
#pragma unroll
    for (int k = 0; k < KPL; ++k) {
        const int j = k * 64 + lane;
        const float w = Wh[j];
        wxs[k] = Wx[j] * C; bxs[k] = bx[j] * C; whn[k] = -2.0f * w; swh += w;
    }
    swh = wave_sum(swh);
    const float bh0 = bh[0];
    const float K0  = bh0 + swh;
    float s = bh0, u = x[b];
    for (int t = 0; t < SEQ - 1; ++t) {
        float u_next = x[(size_t)(t + 1) * BATCH + b];
        const float sc = s * C;
        float p = 0.0f;
#pragma unroll
        for (int k = 0; k < KPL; ++k) {
            float arg = __builtin_fmaf(u, wxs[k], bxs[k]) + sc;
            float r   = fast_rcp(fast_exp2(arg) + 1.0f);
            p = __builtin_fmaf(whn[k], r, p);
        }
        s = K0 + wave_sum(p);
        u = u_next;
    }
    if (lane == 0) s_out[b] = s;
}

__global__ __launch_bounds__(256) void rnn_head_exact(
    const float* __restrict__ x,  const float* __restrict__ Wx,
    const float* __restrict__ bx, const float* __restrict__ Wy,
    const float* __restrict__ by, const float* __restrict__ s_in,
    float* __restrict__ out)
{
    const int lane = threadIdx.x & 63;
    const int wave = threadIdx.x >> 6;
    const int b    = blockIdx.x * 4 + wave;
    const float C  = 2.8853900817779268f;
    const float s  = s_in[b];
    const float u  = x[(size_t)(SEQ - 1) * BATCH + b];
    const float sc = s * C;
    float acc[NOUT];
#pragma unroll
    for (int i = 0; i < NOUT; ++i) acc[i] = 0.0f;
#pragma unroll 4
    for (int k = 0; k < KPL; ++k) {
        const int j = k * 64 + lane;
        float arg = __builtin_fmaf(u, Wx[j] * C, bx[j] * C) + sc;
        float r   = fast_rcp(fast_exp2(arg) + 1.0f);
        float th  = __builtin_fmaf(-2.0f, r, 1.0f);
#pragma unroll
        for (int i = 0; i < NOUT; ++i)
            acc[i] = __builtin_fmaf(Wy[i * HID + j], th, acc[i]);
    }
#pragma unroll
    for (int i = 0; i < NOUT; ++i) acc[i] = wave_sum(acc[i]) + by[i];
    float m = acc[0];
#pragma unroll
    for (int i = 1; i < NOUT; ++i) m = fmaxf(m, acc[i]);
    const float L2E = 1.4426950408889634f;
    float ev[NOUT]; float Z = 0.0f;
#pragma unroll
    for (int i = 0; i < NOUT; ++i) { ev[i] = fast_exp2((acc[i] - m) * L2E); Z += ev[i]; }
    const float rz = fast_rcp(Z);
    if (lane == 0) {
#pragma unroll
        for (int i = 0; i < NOUT; ++i) out[(size_t)b * NOUT + i] = ev[i] * rz;
    }
}

extern "C" void kernel_launch(void* const* d_in, const int* in_sizes, int n_in,
                              void* d_out, int out_size, void* d_ws, size_t ws_size,
                              hipStream_t stream)
{
    const float* x  = (const float*)d_in[0];
    const float* Wx = (const float*)d_in[1];
    const float* bx = (const float*)d_in[2];
    const float* Wh = (const float*)d_in[3];
    const float* bh = (const float*)d_in[4];
    const float* Wy = (const float*)d_in[5];
    const float* by = (const float*)d_in[6];
    float* out = (float*)d_out;
    float* wf  = (float*)d_ws;

    if (ws_size >= (size_t)WSA_FLOATS * sizeof(float)) {
        // R10: one fused launch (+1 tiny memset node for barrier counters)
        hipMemsetAsync(out + CNT_IDX, 0, 2 * sizeof(unsigned), stream);
        k_fused<<<NB, 256, 0, stream>>>(x, Wx, bx, Wh, bh, Wy, by, out, wf);
    } else if (ws_size >= (size_t)WSB_FLOATS * sizeof(float)) {
        // Tier B fallback (R9)
        k_coef<<<NS, 256, 0, stream>>>(Wx, bx, Wh, bh, out);
        k_scan_seg<<<16 + 9 * 16, 256, 0, stream>>>(x, bh, out, wf,
                                                    out + TABLE_FLOATS, wf + 4096, 5, DZ9);
        k_combine<<<16, 256, 0, stream>>>(out + TABLE_FLOATS, wf + 4096, 5, 9, DZ9, wf);
        rnn_head_exact<<<BATCH / 4, 256, 0, stream>>>(x, Wx, bx, Wy, by, wf, out);
    } else {
        rnn_scan_exact<<<BATCH / 4, 256, 0, stream>>>(x, Wx, bx, Wh, bh, wf);
        rnn_head_exact<<<BATCH / 4, 256, 0, stream>>>(x, Wx, bx, Wy, by, wf, out);
    }
}

// Round 11
// 177.872 us; speedup vs baseline: 1.1471x; 1.1471x over previous
//
#include <hip/hip_runtime.h>
#include <math.h>

// VanillaRNN, Wh is (1,H) => scalar recurrence per batch element:
//   s_{t+1} = G(u_t, s_t),  G(u,s) = bh + sum_j wh_j*tanh(wx_j*u + bx_j + s)
// R11: single-launch fusion, FENCE-FREE grid barrier.
//  R10 post-mortem: ~30us per graph node (R6/R9/R10 consistent), and R10's
//  barrier cost ~70us because ACQUIRE polls emit bulk buffer_inv (L1/L2
//  invalidate per poll x 240 CUs) and release fences emit 240x buffer_wbl2.
//  Fix: cross-barrier data (table, z-states) via RELAXED AGENT-scope atomic
//  load/store (bypass non-coherent caches, no bulk ops); barrier = s_waitcnt(0)
//  -> relaxed fetch_add -> relaxed polls. Counter in ws (0xAA-poisoned every
//  launch); base read by all blocks at entry (first increment is >=7us away ->
//  race-free), targets base+224 / base+448. Bounded spin: no hang possible.
//  13 combine nodes (err ~3.4e-4 << 1.59e-2) -> 224 blocks, 1/CU via 83.2KB LDS
//  -> guaranteed co-residency. Wy staged in freed LDS for the head phase.

#define SEQ   512
#define BATCH 4096
#define HID   2048
#define NOUT  10
#define KPL   32
#define NS    560           // s-grid rows over [-10,10]
#define ROWQ  9             // float4s per s-row (8 u-cells + 1 pad)
#define NB    224           // 16 seg0 + 13 nodes x 16 seg1
#define NNODE 13

#define S_LOc   (-10.0f)
#define S_H     (20.0f / 559.0f)
#define S_INVH  (559.0f / 20.0f)
#define S_BIAS  (10.0f * S_INVH)
#define NSM1F   559.0f
#define NSM4F   556.0f
#define U_SCALE (8.0f / 14.0f)
#define U_BIAS  4.0f
#define UCMAXF  7.99951f
#define DZ13    46.5833333f     // 559/12 node spacing (z-units)

#define TABLE_FLOATS (NS * ROWQ * 4)     // 20160 floats (d_out scratch)
// ws layout (floats): [0..4096) z255 ; [4096..57344) 13 node bufs ; [57344] counter
#define CNT_OFF      57344
#define WSF_FLOATS   (CNT_OFF + 2)
// R9 tier-B fallback sizes
#define WSB_FLOATS   (4096 + 4 * 4096)
#define DZ9  69.875f

__device__ __forceinline__ float fast_exp2(float v) { return __builtin_amdgcn_exp2f(v); }
__device__ __forceinline__ float fast_rcp(float v)  { return __builtin_amdgcn_rcpf(v); }
__device__ __forceinline__ float fast_tanh(float a) {
    const float C = 2.8853900817779268f;  // 2*log2(e)
    return __builtin_fmaf(-2.0f, fast_rcp(fast_exp2(C * a) + 1.0f), 1.0f);
}
__device__ __forceinline__ float wave_sum(float v) {
#pragma unroll
    for (int m = 1; m < 64; m <<= 1) v += __shfl_xor(v, m, 64);
    return v;
}

// coherent-point accessors: bypass non-coherent L1/L2, no bulk cache ops
__device__ __forceinline__ void cstore(float* p, float v) {
    __hip_atomic_store(p, v, __ATOMIC_RELAXED, __HIP_MEMORY_SCOPE_AGENT);
}
__device__ __forceinline__ float cload(const float* p) {
    return __hip_atomic_load(p, __ATOMIC_RELAXED, __HIP_MEMORY_SCOPE_AGENT);
}
__device__ __forceinline__ unsigned long long cload64(const unsigned long long* p) {
    return __hip_atomic_load(p, __ATOMIC_RELAXED, __HIP_MEMORY_SCOPE_AGENT);
}

// fence-free grid barrier: prior cstores are already at the coherent point once
// vmcnt drains; arrival/poll are relaxed (no buffer_inv/wbl2). Bounded spin.
__device__ __forceinline__ void grid_barrier(unsigned* cnt, unsigned base, unsigned need) {
    __syncthreads();
    if (threadIdx.x == 0) {
        __builtin_amdgcn_s_waitcnt(0);   // drain vmem/lds before arrival
        __hip_atomic_fetch_add(cnt, 1u, __ATOMIC_RELAXED, __HIP_MEMORY_SCOPE_AGENT);
        for (int it = 0; it < 80000; ++it) {   // ~17ms cap: cannot hang
            unsigned v = __hip_atomic_load(cnt, __ATOMIC_RELAXED, __HIP_MEMORY_SCOPE_AGENT);
            if (v - base >= need) break;
            __builtin_amdgcn_s_sleep(8);
        }
    }
    __syncthreads();
}

// ==================== R11 fused kernel ====================
__global__ __launch_bounds__(256) void k_fused(
    const float* __restrict__ x,  const float* __restrict__ Wx,
    const float* __restrict__ bx, const float* __restrict__ Wh,
    const float* __restrict__ bh, const float* __restrict__ Wy,
    const float* __restrict__ by, float* __restrict__ out,
    float* __restrict__ ws)
{
    __shared__ float4 tabs[5200];                // 83200 B -> pins 1 block/CU
    float* scr = (float*)tabs;
    const int blk = blockIdx.x, tid = threadIdx.x;
    unsigned* cnt = (unsigned*)(ws + CNT_OFF);
    float* tab_g = out;                          // table scratch in d_out

    // read pristine counter (poison) BEFORE any arrivals (first add >=7us away)
    const unsigned base = __hip_atomic_load(cnt, __ATOMIC_RELAXED, __HIP_MEMORY_SCOPE_AGENT);

    // ---------- Phase A: build coefficient table rows blk, blk+224, blk+448 ----------
    {
        const int node = tid & 31, jc = tid >> 5;
        const int cell = node >> 2, nn = node & 3;
        const float xi_n = (nn == 0) ? 0.923879533f : (nn == 1) ? 0.382683432f
                         : (nn == 2) ? -0.382683432f : -0.923879533f;
        const float un = (-7.0f + ((float)cell + 0.5f) * 1.75f) + 0.875f * xi_n;
        for (int r = blk; r < NS; r += NB) {
            const float sn = S_LOc + (float)r * S_H;
            float p = 0.0f;
            const int j0 = jc * 256;
#pragma unroll 4
            for (int j = j0; j < j0 + 256; ++j)
                p += Wh[j] * fast_tanh(__builtin_fmaf(Wx[j], un, bx[j] + sn));
            scr[tid] = p;
            __syncthreads();
            if (tid < 32) {
                float V = bh[0];
#pragma unroll
                for (int c = 0; c < 8; ++c) V += scr[tid + 32 * c];
                scr[256 + tid] = __builtin_fmaf(V, S_INVH, S_BIAS);
            }
            __syncthreads();
            if (tid < 8) {
                const int c = tid;
                float G0 = scr[256 + 4*c], G1 = scr[257 + 4*c], G2 = scr[258 + 4*c], G3 = scr[259 + 4*c];
                float d03 = G0 - G3, d12 = G1 - G2;
                float a0 = 0.25f * (G0 + G1 + G2 + G3);
                float a1 = 0.5f * (0.923879533f * d03 + 0.382683432f * d12);
                float a2 = 0.5f * 0.707106781f * (G0 - G1 - G2 + G3);
                float a3 = 0.5f * (0.382683432f * d03 - 0.923879533f * d12);
                float* q = tab_g + (size_t)(r * ROWQ + c) * 4;
                cstore(q + 0, a0 - a2);          // write-through to coherent point
                cstore(q + 1, a1 - 3.0f * a3);
                cstore(q + 2, 2.0f * a2);
                cstore(q + 3, 4.0f * a3);
            }
            __syncthreads();                     // scr reused next row
        }
    }
    grid_barrier(cnt, base, NB);                 // table globally complete

    // ---------- Phase B: 2-segment speculative scan (R9-validated math) ----------
    {
        const unsigned long long* src64 = (const unsigned long long*)tab_g;
        for (int i = tid; i < NS * ROWQ; i += 256) {   // coherent-point reads
            unsigned long long lo = cload64(src64 + 2 * (size_t)i);
            unsigned long long hi = cload64(src64 + 2 * (size_t)i + 1);
            float2 l = __builtin_bit_cast(float2, lo);
            float2 h = __builtin_bit_cast(float2, hi);
            tabs[i] = make_float4(l.x, l.y, h.x, h.y);
        }
        __syncthreads();

        const int seg  = (blk < 16) ? 0 : 1;
        const int node = seg ? (blk - 16) >> 4 : 0;
        const int eb   = seg ? (blk - 16) & 15 : blk;
        const int b    = eb * 256 + tid;
        const int t0     = seg ? 255 : 0;
        const int nsteps = seg ? 256 : 255;

        float z = seg ? (float)node * DZ13
                      : fminf(fmaxf(__builtin_fmaf(bh[0], S_INVH, S_BIAS), 0.0f), NSM1F);

        auto step1 = [&](float u) {
            float uc = fminf(fmaxf(__builtin_fmaf(u, U_SCALE, U_BIAS), 0.0f), UCMAXF);
            float cf = floorf(uc);
            float xi = __builtin_fmaf(2.0f, uc - cf, -1.0f);
            int   ci = (int)cf;
            float zc  = fminf(fmaxf(z, 0.0f), NSM1F);
            float kzf = fminf(fmaxf(floorf(zc) - 1.0f, 0.0f), NSM4F);
            int   kzi = (int)kzf;
            float ts  = zc - kzf;
            float c0 = ts, c1 = ts - 1.0f, c2 = ts - 2.0f, c3 = ts - 3.0f;
            float n01 = c0 * c1, n23 = c2 * c3;
            float ws0 = c1 * n23 * (-1.0f / 6.0f), ws1 = c0 * n23 * 0.5f;
            float ws2 = n01 * c3 * (-0.5f),        ws3 = n01 * c2 * (1.0f / 6.0f);
            const int base4 = kzi * ROWQ + ci;
            float4 q0 = tabs[base4];
            float4 q1 = tabs[base4 + ROWQ];
            float4 q2 = tabs[base4 + 2 * ROWQ];
            float4 q3 = tabs[base4 + 3 * ROWQ];
            float r0 = __builtin_fmaf(__builtin_fmaf(__builtin_fmaf(q0.w, xi, q0.z), xi, q0.y), xi, q0.x);
            float r1 = __builtin_fmaf(__builtin_fmaf(__builtin_fmaf(q1.w, xi, q1.z), xi, q1.y), xi, q1.x);
            float r2 = __builtin_fmaf(__builtin_fmaf(__builtin_fmaf(q2.w, xi, q2.z), xi, q2.y), xi, q2.x);
            float r3 = __builtin_fmaf(__builtin_fmaf(__builtin_fmaf(q3.w, xi, q3.z), xi, q3.y), xi, q3.x);
            z = __builtin_fmaf(ws0, r0, ws1 * r1) + __builtin_fmaf(ws2, r2, ws3 * r3);
        };

        float cur[8], nxt[8];
#pragma unroll
        for (int i = 0; i < 8; ++i)
            cur[i] = x[(size_t)min(t0 + i, SEQ - 1) * BATCH + b];
        const int full = nsteps >> 3, tail = nsteps & 7;
        for (int c = 0; c < full; ++c) {
            const int nb = t0 + (c + 1) * 8;
#pragma unroll
            for (int i = 0; i < 8; ++i)
                nxt[i] = x[(size_t)min(nb + i, SEQ - 1) * BATCH + b];
#pragma unroll
            for (int i = 0; i < 8; ++i) step1(cur[i]);
#pragma unroll
            for (int i = 0; i < 8; ++i) cur[i] = nxt[i];
        }
        for (int i = 0; i < tail; ++i) step1(cur[i]);

        if (seg == 0) cstore(ws + b, z);
        else          cstore(ws + 4096 + (size_t)node * 4096 + b, z);
    }
    grid_barrier(cnt, base, 2u * NB);            // boundary states complete

    // ---------- Phase C: combine + head; Wy staged in freed LDS ----------
    {
        float* lds_wy = (float*)tabs;            // 81920 B <= 83200
        {
            const float4* wy4 = (const float4*)Wy;
            float4* d4 = (float4*)lds_wy;
            for (int i = tid; i < NOUT * HID / 4; i += 256) d4[i] = wy4[i];
        }
        __syncthreads();
        const int lane = tid & 63;
        const int gw   = blk * 4 + (tid >> 6);   // 0..895
        const float C  = 2.8853900817779268f;
        const float L2E = 1.4426950408889634f;
        for (int e = gw; e < BATCH; e += NB * 4) {
            // piecewise-cubic Lagrange combine over 13 nodes (coherent loads)
            float z255 = cload(ws + e);
            float p = z255 * (1.0f / DZ13);
            int   c = min(max((int)floorf(p) - 1, 0), NNODE - 4);
            float t = p - (float)c;
            float a0 = t, a1 = t - 1.0f, a2 = t - 2.0f, a3 = t - 3.0f;
            float m01 = a0 * a1, m23 = a2 * a3;
            float w0 = a1 * m23 * (-1.0f / 6.0f), w1 = a0 * m23 * 0.5f;
            float w2 = m01 * a3 * (-0.5f),        w3 = m01 * a2 * (1.0f / 6.0f);
            float y0 = cload(ws + 4096 + (size_t)(c + 0) * 4096 + e);
            float y1 = cload(ws + 4096 + (size_t)(c + 1) * 4096 + e);
            float y2 = cload(ws + 4096 + (size_t)(c + 2) * 4096 + e);
            float y3 = cload(ws + 4096 + (size_t)(c + 3) * 4096 + e);
            float zz = __builtin_fmaf(w0, y0, w1 * y1) + __builtin_fmaf(w2, y2, w3 * y3);
            const float s  = __builtin_fmaf(zz, S_H, S_LOc);
            const float u  = x[(size_t)(SEQ - 1) * BATCH + e];
            const float sc = s * C;
            float acc[NOUT];
#pragma unroll
            for (int i = 0; i < NOUT; ++i) acc[i] = 0.0f;
#pragma unroll 4
            for (int k = 0; k < KPL; ++k) {
                const int j = k * 64 + lane;
                float arg = __builtin_fmaf(u, Wx[j] * C, bx[j] * C) + sc;
                float r   = fast_rcp(fast_exp2(arg) + 1.0f);
                float th  = __builtin_fmaf(-2.0f, r, 1.0f);
#pragma unroll
                for (int i = 0; i < NOUT; ++i)
                    acc[i] = __builtin_fmaf(lds_wy[i * HID + j], th, acc[i]);
            }
#pragma unroll
            for (int i = 0; i < NOUT; ++i) acc[i] = wave_sum(acc[i]) + by[i];
            float m = acc[0];
#pragma unroll
            for (int i = 1; i < NOUT; ++i) m = fmaxf(m, acc[i]);
            float ev[NOUT]; float Z = 0.0f;
#pragma unroll
            for (int i = 0; i < NOUT; ++i) { ev[i] = fast_exp2((acc[i] - m) * L2E); Z += ev[i]; }
            const float rz = fast_rcp(Z);
            if (lane == 0) {
#pragma unroll
                for (int i = 0; i < NOUT; ++i) out[(size_t)e * NOUT + i] = ev[i] * rz;
            }
        }
    }
}

// ==================== fallbacks (validated R0/R9) ====================
__device__ __forceinline__ float combine_eval(float z255, int nn, float dz,
                                              const float* baseA, const float* baseB,
                                              int split, int b) {
    float p = z255 / dz;
    int   c = min(max((int)floorf(p) - 1, 0), nn - 4);
    float t = p - (float)c;
    float a0 = t, a1 = t - 1.0f, a2 = t - 2.0f, a3 = t - 3.0f;
    float m01 = a0 * a1, m23 = a2 * a3;
    float w0 = a1 * m23 * (-1.0f / 6.0f), w1 = a0 * m23 * 0.5f;
    float w2 = m01 * a3 * (-0.5f),        w3 = m01 * a2 * (1.0f / 6.0f);
    float y[4];
#pragma unroll
    for (int i = 0; i < 4; ++i) {
        int n = c + i;
        const float* ptr = (n < split) ? (baseA + (size_t)n * 4096)
                                       : (baseB + (size_t)(n - split) * 4096);
        y[i] = ptr[b];
    }
    return __builtin_fmaf(w0, y[0], w1 * y[1]) + __builtin_fmaf(w2, y[2], w3 * y[3]);
}

__global__ __launch_bounds__(256) void k_coef(const float* __restrict__ Wx, const float* __restrict__ bx,
                                              const float* __restrict__ Wh, const float* __restrict__ bh,
                                              float* __restrict__ tab_g) {
    __shared__ float red[256];
    __shared__ float Gn[32];
    const int k    = blockIdx.x;
    const int node = threadIdx.x & 31, jc = threadIdx.x >> 5;
    const int cell = node >> 2, nn = node & 3;
    const float sn = S_LOc + (float)k * S_H;
    const float xi_n = (nn == 0) ? 0.923879533f : (nn == 1) ? 0.382683432f
                     : (nn == 2) ? -0.382683432f : -0.923879533f;
    const float un = (-7.0f + ((float)cell + 0.5f) * 1.75f) + 0.875f * xi_n;
    float p = 0.0f;
    const int j0 = jc * 256;
#pragma unroll 4
    for (int j = j0; j < j0 + 256; ++j)
        p += Wh[j] * fast_tanh(__builtin_fmaf(Wx[j], un, bx[j] + sn));
    red[threadIdx.x] = p;
    __syncthreads();
    if (threadIdx.x < 32) {
        float V = bh[0];
#pragma unroll
        for (int c = 0; c < 8; ++c) V += red[threadIdx.x + 32 * c];
        Gn[threadIdx.x] = __builtin_fmaf(V, S_INVH, S_BIAS);
    }
    __syncthreads();
    float4* wq = (float4*)tab_g;
    if (threadIdx.x < 8) {
        const int c = threadIdx.x;
        float G0 = Gn[4*c+0], G1 = Gn[4*c+1], G2 = Gn[4*c+2], G3 = Gn[4*c+3];
        float d03 = G0 - G3, d12 = G1 - G2;
        float a0 = 0.25f * (G0 + G1 + G2 + G3);
        float a1 = 0.5f * (0.923879533f * d03 + 0.382683432f * d12);
        float a2 = 0.5f * 0.707106781f * (G0 - G1 - G2 + G3);
        float a3 = 0.5f * (0.382683432f * d03 - 0.923879533f * d12);
        wq[k * ROWQ + c] = make_float4(a0 - a2, a1 - 3.0f * a3, 2.0f * a2, 4.0f * a3);
    } else if (threadIdx.x == 8) {
        wq[k * ROWQ + 8] = make_float4(0.f, 0.f, 0.f, 0.f);
    }
}

__global__ __launch_bounds__(256) void k_scan_seg(const float* __restrict__ x,
                                                  const float* __restrict__ bh,
                                                  const float* __restrict__ tab_g,
                                                  float* __restrict__ z255,
                                                  float* __restrict__ baseA,
                                                  float* __restrict__ baseB,
                                                  int split, float dz) {
    __shared__ float4 tabs[5200];
    {
        const float4* src = (const float4*)tab_g;
        for (int i = threadIdx.x; i < NS * ROWQ; i += 256) tabs[i] = src[i];
    }
    __syncthreads();
    const int blk = blockIdx.x;
    const int seg  = (blk < 16) ? 0 : 1;
    const int node = seg ? (blk - 16) >> 4 : 0;
    const int eb   = seg ? (blk - 16) & 15 : blk;
    const int b    = eb * 256 + threadIdx.x;
    const int t0     = seg ? 255 : 0;
    const int nsteps = seg ? 256 : 255;
    float z = seg ? (float)node * dz
                  : fminf(fmaxf(__builtin_fmaf(bh[0], S_INVH, S_BIAS), 0.0f), NSM1F);
    auto step1 = [&](float u) {
        float uc = fminf(fmaxf(__builtin_fmaf(u, U_SCALE, U_BIAS), 0.0f), UCMAXF);
        float cf = floorf(uc);
        float xi = __builtin_fmaf(2.0f, uc - cf, -1.0f);
        int   ci = (int)cf;
        float zc  = fminf(fmaxf(z, 0.0f), NSM1F);
        float kzf = fminf(fmaxf(floorf(zc) - 1.0f, 0.0f), NSM4F);
        int   kzi = (int)kzf;
        float ts  = zc - kzf;
        float c0 = ts, c1 = ts - 1.0f, c2 = ts - 2.0f, c3 = ts - 3.0f;
        float n01 = c0 * c1, n23 = c2 * c3;
        float ws0 = c1 * n23 * (-1.0f / 6.0f), ws1 = c0 * n23 * 0.5f;
        float ws2 = n01 * c3 * (-0.5f),        ws3 = n01 * c2 * (1.0f / 6.0f);
        const int base = kzi * ROWQ + ci;
        float4 q0 = tabs[base];
        float4 q1 = tabs[base + ROWQ];
        float4 q2 = tabs[base + 2 * ROWQ];
        float4 q3 = tabs[base + 3 * ROWQ];
        float r0 = __builtin_fmaf(__builtin_fmaf(__builtin_fmaf(q0.w, xi, q0.z), xi, q0.y), xi, q0.x);
        float r1 = __builtin_fmaf(__builtin_fmaf(__builtin_fmaf(q1.w, xi, q1.z), xi, q1.y), xi, q1.x);
        float r2 = __builtin_fmaf(__builtin_fmaf(__builtin_fmaf(q2.w, xi, q2.z), xi, q2.y), xi, q2.x);
        float r3 = __builtin_fmaf(__builtin_fmaf(__builtin_fmaf(q3.w, xi, q3.z), xi, q3.y), xi, q3.x);
        z = __builtin_fmaf(ws0, r0, ws1 * r1) + __builtin_fmaf(ws2, r2, ws3 * r3);
    };
    float cur[8], nxt[8];
#pragma unroll
    for (int i = 0; i < 8; ++i)
        cur[i] = x[(size_t)min(t0 + i, SEQ - 1) * BATCH + b];
    const int full = nsteps >> 3, tail = nsteps & 7;
    for (int c = 0; c < full; ++c) {
        const int nb = t0 + (c + 1) * 8;
#pragma unroll
        for (int i = 0; i < 8; ++i)
            nxt[i] = x[(size_t)min(nb + i, SEQ - 1) * BATCH + b];
#pragma unroll
        for (int i = 0; i < 8; ++i) step1(cur[i]);
#pragma unroll
        for (int i = 0; i < 8; ++i) cur[i] = nxt[i];
    }
    for (int i = 0; i < tail; ++i) step1(cur[i]);
    if (seg == 0) z255[b] = z;
    else {
        float* p = (node < split) ? (baseA + (size_t)node * 4096)
                                  : (baseB + (size_t)(node - split) * 4096);
        p[b] = z;
    }
}

__global__ __launch_bounds__(256) void k_combine(const float* __restrict__ baseA,
                                                 const float* __restrict__ baseB,
                                                 int split, int nn, float dz,
                                                 float* __restrict__ zs) {
    const int b = blockIdx.x * 256 + threadIdx.x;
    float zz = combine_eval(zs[b], nn, dz, baseA, baseB, split, b);
    zs[b] = __builtin_fmaf(zz, S_H, S_LOc);
}

__global__ __launch_bounds__(256) void rnn_scan_exact(
    const float* __restrict__ x,  const float* __restrict__ Wx,
    const float* __restrict__ bx, const float* __restrict__ Wh,
    const float* __restrict__ bh, float* __restrict__ s_out)
{
    const int lane = threadIdx.x & 63;
    const int wave = threadIdx.x >> 6;
    const int b    = blockIdx.x * 4 + wave;
    const float C = 2.8853900817779268f;
    float wxs[KPL], bxs[KPL], whn[KPL];
    float swh = 0.0f;
#pragma unroll
    for (int k = 0; k < KPL; ++k) {
        const int j = k * 64 + lane;
        const float w = Wh[j];
        wxs[k] = Wx[j] * C; bxs[k] = bx[j] * C; whn[k] = -2.0f * w; swh += w;
    }
    swh = wave_sum(swh);
    const float bh0 = bh[0];
    const float K0  = bh0 + swh;
    float s = bh0, u = x[b];
    for (int t = 0; t < SEQ - 1; ++t) {
        float u_next = x[(size_t)(t + 1) * BATCH + b];
        const float sc = s * C;
        float p = 0.0f;
#pragma unroll
        for (int k = 0; k < KPL; ++k) {
            float arg = __builtin_fmaf(u, wxs[k], bxs[k]) + sc;
            float r   = fast_rcp(fast_exp2(arg) + 1.0f);
            p = __builtin_fmaf(whn[k], r, p);
        }
        s = K0 + wave_sum(p);
        u = u_next;
    }
    if (lane == 0) s_out[b] = s;
}

__global__ __launch_bounds__(256) void rnn_head_exact(
    const float* __restrict__ x,  const float* __restrict__ Wx,
    const float* __restrict__ bx, const float* __restrict__ Wy,
    const float* __restrict__ by, const float* __restrict__ s_in,
    float* __restrict__ out)
{
    const int lane = threadIdx.x & 63;
    const int wave = threadIdx.x >> 6;
    const int b    = blockIdx.x * 4 + wave;
    const float C  = 2.8853900817779268f;
    const float s  = s_in[b];
    const float u  = x[(size_t)(SEQ - 1) * BATCH + b];
    const float sc = s * C;
    float acc[NOUT];
#pragma unroll
    for (int i = 0; i < NOUT; ++i) acc[i] = 0.0f;
#pragma unroll 4
    for (int k = 0; k < KPL; ++k) {
        const int j = k * 64 + lane;
        float arg = __builtin_fmaf(u, Wx[j] * C, bx[j] * C) + sc;
        float r   = fast_rcp(fast_exp2(arg) + 1.0f);
        float th  = __builtin_fmaf(-2.0f, r, 1.0f);
#pragma unroll
        for (int i = 0; i < NOUT; ++i)
            acc[i] = __builtin_fmaf(Wy[i * HID + j], th, acc[i]);
    }
#pragma unroll
    for (int i = 0; i < NOUT; ++i) acc[i] = wave_sum(acc[i]) + by[i];
    float m = acc[0];
#pragma unroll
    for (int i = 1; i < NOUT; ++i) m = fmaxf(m, acc[i]);
    const float L2E = 1.4426950408889634f;
    float ev[NOUT]; float Z = 0.0f;
#pragma unroll
    for (int i = 0; i < NOUT; ++i) { ev[i] = fast_exp2((acc[i] - m) * L2E); Z += ev[i]; }
    const float rz = fast_rcp(Z);
    if (lane == 0) {
#pragma unroll
        for (int i = 0; i < NOUT; ++i) out[(size_t)b * NOUT + i] = ev[i] * rz;
    }
}

extern "C" void kernel_launch(void* const* d_in, const int* in_sizes, int n_in,
                              void* d_out, int out_size, void* d_ws, size_t ws_size,
                              hipStream_t stream)
{
    const float* x  = (const float*)d_in[0];
    const float* Wx = (const float*)d_in[1];
    const float* bx = (const float*)d_in[2];
    const float* Wh = (const float*)d_in[3];
    const float* bh = (const float*)d_in[4];
    const float* Wy = (const float*)d_in[5];
    const float* by = (const float*)d_in[6];
    float* out = (float*)d_out;
    float* wf  = (float*)d_ws;

    if (ws_size >= (size_t)WSF_FLOATS * sizeof(float)) {
        // R11: ONE graph node, fence-free internal barriers
        k_fused<<<NB, 256, 0, stream>>>(x, Wx, bx, Wh, bh, Wy, by, out, wf);
    } else if (ws_size >= (size_t)WSB_FLOATS * sizeof(float)) {
        // Tier B fallback (R9)
        k_coef<<<NS, 256, 0, stream>>>(Wx, bx, Wh, bh, out);
        k_scan_seg<<<16 + 9 * 16, 256, 0, stream>>>(x, bh, out, wf,
                                                    out + TABLE_FLOATS, wf + 4096, 5, DZ9);
        k_combine<<<16, 256, 0, stream>>>(out + TABLE_FLOATS, wf + 4096, 5, 9, DZ9, wf);
        rnn_head_exact<<<BATCH / 4, 256, 0, stream>>>(x, Wx, bx, Wy, by, wf, out);
    } else {
        rnn_scan_exact<<<BATCH / 4, 256, 0, stream>>>(x, Wx, bx, Wh, bh, wf);
        rnn_head_exact<<<BATCH / 4, 256, 0, stream>>>(x, Wx, bx, Wy, by, wf, out);
    }
}

// Round 12
// 158.449 us; speedup vs baseline: 1.2877x; 1.1226x over previous
//
#include <hip/hip_runtime.h>
#include <math.h>

// VanillaRNN, Wh is (1,H) => scalar recurrence per batch element:
//   s_{t+1} = G(u_t, s_t),  G(u,s) = bh + sum_j wh_j*tanh(wx_j*u + bx_j + s)
// R12: TWO nodes. Node1 = k_coef (proven standalone, 560 blocks, multi-wave).
// Node2 = scan -> internal fence-free barrier -> combine+head.
//  - R11 post-mortem: harness gap is ~58us fixed + ~8us/extra node (NOT
//    30/node); R11's fused kernel carried ~50us in-kernel anomaly. Suspects:
//    phase A at 1 block/CU (transcendental latency exposed) + atomic-load
//    table copy. Both are removed here: table crosses a kernel boundary ->
//    plain cached float4 loads; k_coef runs at 2.2 blocks/CU.
//  - 14 nodes (REVERT from R11's 13: absmax 2.44e-4 -> 1.95e-3 measured).
//  - Barrier counter = pristine 0xAA poison in d_out[40956], read by all
//    blocks at entry (first increment ~40us later). Post-barrier head
//    overwrite is safe: any float bit pattern exits the poll window.
//  - Bounded spin -> cannot hang.

#define SEQ   512
#define BATCH 4096
#define HID   2048
#define NOUT  10
#define KPL   32
#define NS    560           // s-grid rows over [-10,10]
#define ROWQ  9             // float4s per s-row (8 u-cells + 1 pad)
#define NB    240           // node2 grid: 16 seg0 + 14 nodes x 16 seg1
#define NNODE 14

#define S_LOc   (-10.0f)
#define S_H     (20.0f / 559.0f)
#define S_INVH  (559.0f / 20.0f)
#define S_BIAS  (10.0f * S_INVH)
#define NSM1F   559.0f
#define NSM4F   556.0f
#define U_SCALE (8.0f / 14.0f)
#define U_BIAS  4.0f
#define UCMAXF  7.99951f
#define DZ14    43.0f           // 559/13, exact

#define TABLE_FLOATS (NS * ROWQ * 4)     // 20160 floats (d_out scratch)
#define CNT_IDX      40956               // counter in d_out tail (poison-based)
#define WSA_FLOATS   (4096 + 14 * 4096)  // z255 + 14 node bufs (ws) = R9-proven
#define WSB_FLOATS   (4096 + 4 * 4096)
#define DZ9  69.875f

__device__ __forceinline__ float fast_exp2(float v) { return __builtin_amdgcn_exp2f(v); }
__device__ __forceinline__ float fast_rcp(float v)  { return __builtin_amdgcn_rcpf(v); }
__device__ __forceinline__ float fast_tanh(float a) {
    const float C = 2.8853900817779268f;  // 2*log2(e)
    return __builtin_fmaf(-2.0f, fast_rcp(fast_exp2(C * a) + 1.0f), 1.0f);
}
__device__ __forceinline__ float wave_sum(float v) {
#pragma unroll
    for (int m = 1; m < 64; m <<= 1) v += __shfl_xor(v, m, 64);
    return v;
}

// coherent-point accessors (relaxed agent scope: no bulk cache ops)
__device__ __forceinline__ void cstore(float* p, float v) {
    __hip_atomic_store(p, v, __ATOMIC_RELAXED, __HIP_MEMORY_SCOPE_AGENT);
}
__device__ __forceinline__ float cload(const float* p) {
    return __hip_atomic_load(p, __ATOMIC_RELAXED, __HIP_MEMORY_SCOPE_AGENT);
}

// ---------------- K1 (node 1): coefficient table -> d_out[0..20160) ----------------
__global__ __launch_bounds__(256) void k_coef(const float* __restrict__ Wx, const float* __restrict__ bx,
                                              const float* __restrict__ Wh, const float* __restrict__ bh,
                                              float* __restrict__ tab_g) {
    __shared__ float red[256];
    __shared__ float Gn[32];
    const int k    = blockIdx.x;
    const int node = threadIdx.x & 31, jc = threadIdx.x >> 5;
    const int cell = node >> 2, nn = node & 3;
    const float sn = S_LOc + (float)k * S_H;
    const float xi_n = (nn == 0) ? 0.923879533f : (nn == 1) ? 0.382683432f
                     : (nn == 2) ? -0.382683432f : -0.923879533f;
    const float un = (-7.0f + ((float)cell + 0.5f) * 1.75f) + 0.875f * xi_n;
    float p = 0.0f;
    const int j0 = jc * 256;
#pragma unroll 4
    for (int j = j0; j < j0 + 256; ++j)
        p += Wh[j] * fast_tanh(__builtin_fmaf(Wx[j], un, bx[j] + sn));
    red[threadIdx.x] = p;
    __syncthreads();
    if (threadIdx.x < 32) {
        float V = bh[0];
#pragma unroll
        for (int c = 0; c < 8; ++c) V += red[threadIdx.x + 32 * c];
        Gn[threadIdx.x] = __builtin_fmaf(V, S_INVH, S_BIAS);
    }
    __syncthreads();
    float4* wq = (float4*)tab_g;
    if (threadIdx.x < 8) {
        const int c = threadIdx.x;
        float G0 = Gn[4*c+0], G1 = Gn[4*c+1], G2 = Gn[4*c+2], G3 = Gn[4*c+3];
        float d03 = G0 - G3, d12 = G1 - G2;
        float a0 = 0.25f * (G0 + G1 + G2 + G3);
        float a1 = 0.5f * (0.923879533f * d03 + 0.382683432f * d12);
        float a2 = 0.5f * 0.707106781f * (G0 - G1 - G2 + G3);
        float a3 = 0.5f * (0.382683432f * d03 - 0.923879533f * d12);
        wq[k * ROWQ + c] = make_float4(a0 - a2, a1 - 3.0f * a3, 2.0f * a2, 4.0f * a3);
    } else if (threadIdx.x == 8) {
        wq[k * ROWQ + 8] = make_float4(0.f, 0.f, 0.f, 0.f);
    }
}

// ---------------- K2 (node 2): scan -> barrier -> combine + head ----------------
__global__ __launch_bounds__(256) void k_scanhead(
    const float* __restrict__ x,  const float* __restrict__ Wx,
    const float* __restrict__ bx, const float* __restrict__ bh,
    const float* __restrict__ Wy, const float* __restrict__ by,
    float* __restrict__ out, float* __restrict__ ws)
{
    __shared__ float4 tabs[5200];                // 83200 B -> pins 1 block/CU
    const int blk = blockIdx.x, tid = threadIdx.x;
    unsigned* cnt = (unsigned*)out + CNT_IDX;

    // pristine poison counter base, read before any arrival (~40us margin)
    const unsigned base = __hip_atomic_load(cnt, __ATOMIC_RELAXED, __HIP_MEMORY_SCOPE_AGENT);

    // ---- table -> LDS (plain cached loads: producer was a separate kernel) ----
    {
        const float4* src = (const float4*)out;  // table lives in d_out[0..20160)
        for (int i = tid; i < NS * ROWQ; i += 256) tabs[i] = src[i];
    }
    __syncthreads();

    // ---- Phase B: 2-segment speculative scan (R9-validated) ----
    {
        const int seg  = (blk < 16) ? 0 : 1;
        const int node = seg ? (blk - 16) >> 4 : 0;
        const int eb   = seg ? (blk - 16) & 15 : blk;
        const int b    = eb * 256 + tid;
        const int t0     = seg ? 255 : 0;
        const int nsteps = seg ? 256 : 255;

        float z = seg ? (float)node * DZ14
                      : fminf(fmaxf(__builtin_fmaf(bh[0], S_INVH, S_BIAS), 0.0f), NSM1F);

        auto step1 = [&](float u) {
            float uc = fminf(fmaxf(__builtin_fmaf(u, U_SCALE, U_BIAS), 0.0f), UCMAXF);
            float cf = floorf(uc);
            float xi = __builtin_fmaf(2.0f, uc - cf, -1.0f);
            int   ci = (int)cf;
            float zc  = fminf(fmaxf(z, 0.0f), NSM1F);
            float kzf = fminf(fmaxf(floorf(zc) - 1.0f, 0.0f), NSM4F);
            int   kzi = (int)kzf;
            float ts  = zc - kzf;
            float c0 = ts, c1 = ts - 1.0f, c2 = ts - 2.0f, c3 = ts - 3.0f;
            float n01 = c0 * c1, n23 = c2 * c3;
            float ws0 = c1 * n23 * (-1.0f / 6.0f), ws1 = c0 * n23 * 0.5f;
            float ws2 = n01 * c3 * (-0.5f),        ws3 = n01 * c2 * (1.0f / 6.0f);
            const int base4 = kzi * ROWQ + ci;
            float4 q0 = tabs[base4];
            float4 q1 = tabs[base4 + ROWQ];
            float4 q2 = tabs[base4 + 2 * ROWQ];
            float4 q3 = tabs[base4 + 3 * ROWQ];
            float r0 = __builtin_fmaf(__builtin_fmaf(__builtin_fmaf(q0.w, xi, q0.z), xi, q0.y), xi, q0.x);
            float r1 = __builtin_fmaf(__builtin_fmaf(__builtin_fmaf(q1.w, xi, q1.z), xi, q1.y), xi, q1.x);
            float r2 = __builtin_fmaf(__builtin_fmaf(__builtin_fmaf(q2.w, xi, q2.z), xi, q2.y), xi, q2.x);
            float r3 = __builtin_fmaf(__builtin_fmaf(__builtin_fmaf(q3.w, xi, q3.z), xi, q3.y), xi, q3.x);
            z = __builtin_fmaf(ws0, r0, ws1 * r1) + __builtin_fmaf(ws2, r2, ws3 * r3);
        };

        float cur[8], nxt[8];
#pragma unroll
        for (int i = 0; i < 8; ++i)
            cur[i] = x[(size_t)min(t0 + i, SEQ - 1) * BATCH + b];
        const int full = nsteps >> 3, tail = nsteps & 7;
        for (int c = 0; c < full; ++c) {
            const int nb = t0 + (c + 1) * 8;
#pragma unroll
            for (int i = 0; i < 8; ++i)
                nxt[i] = x[(size_t)min(nb + i, SEQ - 1) * BATCH + b];
#pragma unroll
            for (int i = 0; i < 8; ++i) step1(cur[i]);
#pragma unroll
            for (int i = 0; i < 8; ++i) cur[i] = nxt[i];
        }
        for (int i = 0; i < tail; ++i) step1(cur[i]);

        if (seg == 0) cstore(ws + b, z);
        else          cstore(ws + 4096 + (size_t)node * 4096 + b, z);
    }

    // ---- fence-free grid barrier (single, need = 240 arrivals) ----
    __syncthreads();
    if (tid == 0) {
        __builtin_amdgcn_s_waitcnt(0);           // drain cstores before arrival
        __hip_atomic_fetch_add(cnt, 1u, __ATOMIC_RELAXED, __HIP_MEMORY_SCOPE_AGENT);
        for (int it = 0; it < 80000; ++it) {     // ~17ms cap: cannot hang
            unsigned v = __hip_atomic_load(cnt, __ATOMIC_RELAXED, __HIP_MEMORY_SCOPE_AGENT);
            if (v - base >= (unsigned)NB) break; // float overwrite also exits
            __builtin_amdgcn_s_sleep(8);
        }
    }
    __syncthreads();

    // ---- Phase C: combine + head; Wy staged in freed LDS ----
    {
        float* lds_wy = (float*)tabs;            // 81920 B <= 83200
        {
            const float4* wy4 = (const float4*)Wy;
            float4* d4 = (float4*)lds_wy;
            for (int i = tid; i < NOUT * HID / 4; i += 256) d4[i] = wy4[i];
        }
        __syncthreads();
        const int lane = tid & 63;
        const int gw   = blk * 4 + (tid >> 6);   // 0..959
        const float C  = 2.8853900817779268f;
        const float L2E = 1.4426950408889634f;
        for (int e = gw; e < BATCH; e += NB * 4) {
            float z255 = cload(ws + e);
            float p = z255 * (1.0f / DZ14);
            int   c = min(max((int)floorf(p) - 1, 0), NNODE - 4);
            float t = p - (float)c;
            float a0 = t, a1 = t - 1.0f, a2 = t - 2.0f, a3 = t - 3.0f;
            float m01 = a0 * a1, m23 = a2 * a3;
            float w0 = a1 * m23 * (-1.0f / 6.0f), w1 = a0 * m23 * 0.5f;
            float w2 = m01 * a3 * (-0.5f),        w3 = m01 * a2 * (1.0f / 6.0f);
            float y0 = cload(ws + 4096 + (size_t)(c + 0) * 4096 + e);
            float y1 = cload(ws + 4096 + (size_t)(c + 1) * 4096 + e);
            float y2 = cload(ws + 4096 + (size_t)(c + 2) * 4096 + e);
            float y3 = cload(ws + 4096 + (size_t)(c + 3) * 4096 + e);
            float zz = __builtin_fmaf(w0, y0, w1 * y1) + __builtin_fmaf(w2, y2, w3 * y3);
            const float s  = __builtin_fmaf(zz, S_H, S_LOc);
            const float u  = x[(size_t)(SEQ - 1) * BATCH + e];
            const float sc = s * C;
            float acc[NOUT];
#pragma unroll
            for (int i = 0; i < NOUT; ++i) acc[i] = 0.0f;
#pragma unroll 4
            for (int k = 0; k < KPL; ++k) {
                const int j = k * 64 + lane;
                float arg = __builtin_fmaf(u, Wx[j] * C, bx[j] * C) + sc;
                float r   = fast_rcp(fast_exp2(arg) + 1.0f);
                float th  = __builtin_fmaf(-2.0f, r, 1.0f);
#pragma unroll
                for (int i = 0; i < NOUT; ++i)
                    acc[i] = __builtin_fmaf(lds_wy[i * HID + j], th, acc[i]);
            }
#pragma unroll
            for (int i = 0; i < NOUT; ++i) acc[i] = wave_sum(acc[i]) + by[i];
            float m = acc[0];
#pragma unroll
            for (int i = 1; i < NOUT; ++i) m = fmaxf(m, acc[i]);
            float ev[NOUT]; float Z = 0.0f;
#pragma unroll
            for (int i = 0; i < NOUT; ++i) { ev[i] = fast_exp2((acc[i] - m) * L2E); Z += ev[i]; }
            const float rz = fast_rcp(Z);
            if (lane == 0) {
#pragma unroll
                for (int i = 0; i < NOUT; ++i) out[(size_t)e * NOUT + i] = ev[i] * rz;
            }
        }
    }
}

// ==================== fallbacks (validated R0/R9) ====================
__device__ __forceinline__ float combine_eval(float z255, int nn, float dz,
                                              const float* baseA, const float* baseB,
                                              int split, int b) {
    float p = z255 / dz;
    int   c = min(max((int)floorf(p) - 1, 0), nn - 4);
    float t = p - (float)c;
    float a0 = t, a1 = t - 1.0f, a2 = t - 2.0f, a3 = t - 3.0f;
    float m01 = a0 * a1, m23 = a2 * a3;
    float w0 = a1 * m23 * (-1.0f / 6.0f), w1 = a0 * m23 * 0.5f;
    float w2 = m01 * a3 * (-0.5f),        w3 = m01 * a2 * (1.0f / 6.0f);
    float y[4];
#pragma unroll
    for (int i = 0; i < 4; ++i) {
        int n = c + i;
        const float* ptr = (n < split) ? (baseA + (size_t)n * 4096)
                                       : (baseB + (size_t)(n - split) * 4096);
        y[i] = ptr[b];
    }
    return __builtin_fmaf(w0, y[0], w1 * y[1]) + __builtin_fmaf(w2, y[2], w3 * y[3]);
}

__global__ __launch_bounds__(256) void k_scan_seg(const float* __restrict__ x,
                                                  const float* __restrict__ bh,
                                                  const float* __restrict__ tab_g,
                                                  float* __restrict__ z255,
                                                  float* __restrict__ baseA,
                                                  float* __restrict__ baseB,
                                                  int split, float dz) {
    __shared__ float4 tabs[5200];
    {
        const float4* src = (const float4*)tab_g;
        for (int i = threadIdx.x; i < NS * ROWQ; i += 256) tabs[i] = src[i];
    }
    __syncthreads();
    const int blk = blockIdx.x;
    const int seg  = (blk < 16) ? 0 : 1;
    const int node = seg ? (blk - 16) >> 4 : 0;
    const int eb   = seg ? (blk - 16) & 15 : blk;
    const int b    = eb * 256 + threadIdx.x;
    const int t0     = seg ? 255 : 0;
    const int nsteps = seg ? 256 : 255;
    float z = seg ? (float)node * dz
                  : fminf(fmaxf(__builtin_fmaf(bh[0], S_INVH, S_BIAS), 0.0f), NSM1F);
    auto step1 = [&](float u) {
        float uc = fminf(fmaxf(__builtin_fmaf(u, U_SCALE, U_BIAS), 0.0f), UCMAXF);
        float cf = floorf(uc);
        float xi = __builtin_fmaf(2.0f, uc - cf, -1.0f);
        int   ci = (int)cf;
        float zc  = fminf(fmaxf(z, 0.0f), NSM1F);
        float kzf = fminf(fmaxf(floorf(zc) - 1.0f, 0.0f), NSM4F);
        int   kzi = (int)kzf;
        float ts  = zc - kzf;
        float c0 = ts, c1 = ts - 1.0f, c2 = ts - 2.0f, c3 = ts - 3.0f;
        float n01 = c0 * c1, n23 = c2 * c3;
        float ws0 = c1 * n23 * (-1.0f / 6.0f), ws1 = c0 * n23 * 0.5f;
        float ws2 = n01 * c3 * (-0.5f),        ws3 = n01 * c2 * (1.0f / 6.0f);
        const int base = kzi * ROWQ + ci;
        float4 q0 = tabs[base];
        float4 q1 = tabs[base + ROWQ];
        float4 q2 = tabs[base + 2 * ROWQ];
        float4 q3 = tabs[base + 3 * ROWQ];
        float r0 = __builtin_fmaf(__builtin_fmaf(__builtin_fmaf(q0.w, xi, q0.z), xi, q0.y), xi, q0.x);
        float r1 = __builtin_fmaf(__builtin_fmaf(__builtin_fmaf(q1.w, xi, q1.z), xi, q1.y), xi, q1.x);
        float r2 = __builtin_fmaf(__builtin_fmaf(__builtin_fmaf(q2.w, xi, q2.z), xi, q2.y), xi, q2.x);
        float r3 = __builtin_fmaf(__builtin_fmaf(__builtin_fmaf(q3.w, xi, q3.z), xi, q3.y), xi, q3.x);
        z = __builtin_fmaf(ws0, r0, ws1 * r1) + __builtin_fmaf(ws2, r2, ws3 * r3);
    };
    float cur[8], nxt[8];
#pragma unroll
    for (int i = 0; i < 8; ++i)
        cur[i] = x[(size_t)min(t0 + i, SEQ - 1) * BATCH + b];
    const int full = nsteps >> 3, tail = nsteps & 7;
    for (int c = 0; c < full; ++c) {
        const int nb = t0 + (c + 1) * 8;
#pragma unroll
        for (int i = 0; i < 8; ++i)
            nxt[i] = x[(size_t)min(nb + i, SEQ - 1) * BATCH + b];
#pragma unroll
        for (int i = 0; i < 8; ++i) step1(cur[i]);
#pragma unroll
        for (int i = 0; i < 8; ++i) cur[i] = nxt[i];
    }
    for (int i = 0; i < tail; ++i) step1(cur[i]);
    if (seg == 0) z255[b] = z;
    else {
        float* p = (node < split) ? (baseA + (size_t)node * 4096)
                                  : (baseB + (size_t)(node - split) * 4096);
        p[b] = z;
    }
}

__global__ __launch_bounds__(256) void k_combine(const float* __restrict__ baseA,
                                                 const float* __restrict__ baseB,
                                                 int split, int nn, float dz,
                                                 float* __restrict__ zs) {
    const int b = blockIdx.x * 256 + threadIdx.x;
    float zz = combine_eval(zs[b], nn, dz, baseA, baseB, split, b);
    zs[b] = __builtin_fmaf(zz, S_H, S_LOc);
}

__global__ __launch_bounds__(256) void rnn_scan_exact(
    const float* __restrict__ x,  const float* __restrict__ Wx,
    const float* __restrict__ bx, const float* __restrict__ Wh,
    const float* __restrict__ bh, float* __restrict__ s_out)
{
    const int lane = threadIdx.x & 63;
    const int wave = threadIdx.x >> 6;
    const int b    = blockIdx.x * 4 + wave;
    const float C = 2.8853900817779268f;
    float wxs[KPL], bxs[KPL], whn[KPL];
    float swh = 0.0f;
#pragma unroll
    for (int k = 0; k < KPL; ++k) {
        const int j = k * 64 + lane;
        const float w = Wh[j];
        wxs[k] = Wx[j] * C; bxs[k] = bx[j] * C; whn[k] = -2.0f * w; swh += w;
    }
    swh = wave_sum(swh);
    const float bh0 = bh[0];
    const float K0  = bh0 + swh;
    float s = bh0, u = x[b];
    for (int t = 0; t < SEQ - 1; ++t) {
        float u_next = x[(size_t)(t + 1) * BATCH + b];
        const float sc = s * C;
        float p = 0.0f;
#pragma unroll
        for (int k = 0; k < KPL; ++k) {
            float arg = __builtin_fmaf(u, wxs[k], bxs[k]) + sc;
            float r   = fast_rcp(fast_exp2(arg) + 1.0f);
            p = __builtin_fmaf(whn[k], r, p);
        }
        s = K0 + wave_sum(p);
        u = u_next;
    }
    if (lane == 0) s_out[b] = s;
}

__global__ __launch_bounds__(256) void rnn_head_exact(
    const float* __restrict__ x,  const float* __restrict__ Wx,
    const float* __restrict__ bx, const float* __restrict__ Wy,
    const float* __restrict__ by, const float* __restrict__ s_in,
    float* __restrict__ out)
{
    const int lane = threadIdx.x & 63;
    const int wave = threadIdx.x >> 6;
    const int b    = blockIdx.x * 4 + wave;
    const float C  = 2.8853900817779268f;
    const float s  = s_in[b];
    const float u  = x[(size_t)(SEQ - 1) * BATCH + b];
    const float sc = s * C;
    float acc[NOUT];
#pragma unroll
    for (int i = 0; i < NOUT; ++i) acc[i] = 0.0f;
#pragma unroll 4
    for (int k = 0; k < KPL; ++k) {
        const int j = k * 64 + lane;
        float arg = __builtin_fmaf(u, Wx[j] * C, bx[j] * C) + sc;
        float r   = fast_rcp(fast_exp2(arg) + 1.0f);
        float th  = __builtin_fmaf(-2.0f, r, 1.0f);
#pragma unroll
        for (int i = 0; i < NOUT; ++i)
            acc[i] = __builtin_fmaf(Wy[i * HID + j], th, acc[i]);
    }
#pragma unroll
    for (int i = 0; i < NOUT; ++i) acc[i] = wave_sum(acc[i]) + by[i];
    float m = acc[0];
#pragma unroll
    for (int i = 1; i < NOUT; ++i) m = fmaxf(m, acc[i]);
    const float L2E = 1.4426950408889634f;
    float ev[NOUT]; float Z = 0.0f;
#pragma unroll
    for (int i = 0; i < NOUT; ++i) { ev[i] = fast_exp2((acc[i] - m) * L2E); Z += ev[i]; }
    const float rz = fast_rcp(Z);
    if (lane == 0) {
#pragma unroll
        for (int i = 0; i < NOUT; ++i) out[(size_t)b * NOUT + i] = ev[i] * rz;
    }
}

extern "C" void kernel_launch(void* const* d_in, const int* in_sizes, int n_in,
                              void* d_out, int out_size, void* d_ws, size_t ws_size,
                              hipStream_t stream)
{
    const float* x  = (const float*)d_in[0];
    const float* Wx = (const float*)d_in[1];
    const float* bx = (const float*)d_in[2];
    const float* Wh = (const float*)d_in[3];
    const float* bh = (const float*)d_in[4];
    const float* Wy = (const float*)d_in[5];
    const float* by = (const float*)d_in[6];
    float* out = (float*)d_out;
    float* wf  = (float*)d_ws;

    if (ws_size >= (size_t)WSA_FLOATS * sizeof(float)) {
        // R12: two nodes — coef, then fused scan+combine+head
        k_coef<<<NS, 256, 0, stream>>>(Wx, bx, Wh, bh, out);
        k_scanhead<<<NB, 256, 0, stream>>>(x, Wx, bx, bh, Wy, by, out, wf);
    } else if (ws_size >= (size_t)WSB_FLOATS * sizeof(float)) {
        // Tier B fallback (R9)
        k_coef<<<NS, 256, 0, stream>>>(Wx, bx, Wh, bh, out);
        k_scan_seg<<<16 + 9 * 16, 256, 0, stream>>>(x, bh, out, wf,
                                                    out + TABLE_FLOATS, wf + 4096, 5, DZ9);
        k_combine<<<16, 256, 0, stream>>>(out + TABLE_FLOATS, wf + 4096, 5, 9, DZ9, wf);
        rnn_head_exact<<<BATCH / 4, 256, 0, stream>>>(x, Wx, bx, Wy, by, wf, out);
    } else {
        rnn_scan_exact<<<BATCH / 4, 256, 0, stream>>>(x, Wx, bx, Wh, bh, wf);
        rnn_head_exact<<<BATCH / 4, 256, 0, stream>>>(x, Wx, bx, Wy, by, wf, out);
    }
}

// Round 13
// 153.380 us; speedup vs baseline: 1.3302x; 1.0331x over previous
//
#include <hip/hip_runtime.h>
#include <math.h>

// VanillaRNN, Wh is (1,H) => scalar recurrence per batch element:
//   s_{t+1} = G(u_t, s_t),  G(u,s) = bh + sum_j wh_j*tanh(wx_j*u + bx_j + s)
// R13: R12's 2-node pipeline with the global grid barrier replaced by 16
// PER-GROUP barriers (15 arrivals each, counters 64B apart -> parallel).
//  R12 post-mortem: k_scanhead = scan(47) + head(5) + ~30us barrier. The 30us
//  matches 240 far-atomic arrivals serializing on ONE address (~300cyc each).
//  Group eb's combine needs only its own 15 producer blocks -> 16 independent
//  barriers of 15 arrivals ~2us total. Post-barrier the group's 60 waves do
//  combine+head for their 256 elements (Wy direct from global, R9-proven).
//  Counters in ws[WSA..WSA+256) (nothing else writes there -> no clobber /
//  spurious-exit). If ws is too small for the counter tail, the SAME kernel
//  runs in global-barrier mode (= R12's measured 158us behavior).

#define SEQ   512
#define BATCH 4096
#define HID   2048
#define NOUT  10
#define KPL   32
#define NS    560           // s-grid rows over [-10,10]
#define ROWQ  9             // float4s per s-row (8 u-cells + 1 pad)
#define NB    240           // 16 seg0 + 14 nodes x 16 seg1
#define NNODE 14

#define S_LOc   (-10.0f)
#define S_H     (20.0f / 559.0f)
#define S_INVH  (559.0f / 20.0f)
#define S_BIAS  (10.0f * S_INVH)
#define NSM1F   559.0f
#define NSM4F   556.0f
#define U_SCALE (8.0f / 14.0f)
#define U_BIAS  4.0f
#define UCMAXF  7.99951f
#define DZ14    43.0f           // 559/13, exact

#define TABLE_FLOATS (NS * ROWQ * 4)     // 20160 floats (d_out scratch)
#define CNT_IDX      40956               // global-mode counter in d_out tail
#define WSA_FLOATS   (4096 + 14 * 4096)  // z255 + 14 node bufs (R9-proven size)
#define WSG_FLOATS   (WSA_FLOATS + 256)  // + 16 group counters, 16-float spacing
#define WSB_FLOATS   (4096 + 4 * 4096)
#define DZ9  69.875f

__device__ __forceinline__ float fast_exp2(float v) { return __builtin_amdgcn_exp2f(v); }
__device__ __forceinline__ float fast_rcp(float v)  { return __builtin_amdgcn_rcpf(v); }
__device__ __forceinline__ float fast_tanh(float a) {
    const float C = 2.8853900817779268f;  // 2*log2(e)
    return __builtin_fmaf(-2.0f, fast_rcp(fast_exp2(C * a) + 1.0f), 1.0f);
}
__device__ __forceinline__ float wave_sum(float v) {
#pragma unroll
    for (int m = 1; m < 64; m <<= 1) v += __shfl_xor(v, m, 64);
    return v;
}

// coherent-point accessors (relaxed agent scope: no bulk cache ops)
__device__ __forceinline__ void cstore(float* p, float v) {
    __hip_atomic_store(p, v, __ATOMIC_RELAXED, __HIP_MEMORY_SCOPE_AGENT);
}
__device__ __forceinline__ float cload(const float* p) {
    return __hip_atomic_load(p, __ATOMIC_RELAXED, __HIP_MEMORY_SCOPE_AGENT);
}

// ---------------- K1 (node 1): coefficient table -> d_out[0..20160) ----------------
__global__ __launch_bounds__(256) void k_coef(const float* __restrict__ Wx, const float* __restrict__ bx,
                                              const float* __restrict__ Wh, const float* __restrict__ bh,
                                              float* __restrict__ tab_g) {
    __shared__ float red[256];
    __shared__ float Gn[32];
    const int k    = blockIdx.x;
    const int node = threadIdx.x & 31, jc = threadIdx.x >> 5;
    const int cell = node >> 2, nn = node & 3;
    const float sn = S_LOc + (float)k * S_H;
    const float xi_n = (nn == 0) ? 0.923879533f : (nn == 1) ? 0.382683432f
                     : (nn == 2) ? -0.382683432f : -0.923879533f;
    const float un = (-7.0f + ((float)cell + 0.5f) * 1.75f) + 0.875f * xi_n;
    float p = 0.0f;
    const int j0 = jc * 256;
#pragma unroll 4
    for (int j = j0; j < j0 + 256; ++j)
        p += Wh[j] * fast_tanh(__builtin_fmaf(Wx[j], un, bx[j] + sn));
    red[threadIdx.x] = p;
    __syncthreads();
    if (threadIdx.x < 32) {
        float V = bh[0];
#pragma unroll
        for (int c = 0; c < 8; ++c) V += red[threadIdx.x + 32 * c];
        Gn[threadIdx.x] = __builtin_fmaf(V, S_INVH, S_BIAS);
    }
    __syncthreads();
    float4* wq = (float4*)tab_g;
    if (threadIdx.x < 8) {
        const int c = threadIdx.x;
        float G0 = Gn[4*c+0], G1 = Gn[4*c+1], G2 = Gn[4*c+2], G3 = Gn[4*c+3];
        float d03 = G0 - G3, d12 = G1 - G2;
        float a0 = 0.25f * (G0 + G1 + G2 + G3);
        float a1 = 0.5f * (0.923879533f * d03 + 0.382683432f * d12);
        float a2 = 0.5f * 0.707106781f * (G0 - G1 - G2 + G3);
        float a3 = 0.5f * (0.382683432f * d03 - 0.923879533f * d12);
        wq[k * ROWQ + c] = make_float4(a0 - a2, a1 - 3.0f * a3, 2.0f * a2, 4.0f * a3);
    } else if (threadIdx.x == 8) {
        wq[k * ROWQ + 8] = make_float4(0.f, 0.f, 0.f, 0.f);
    }
}

// ---------------- K2 (node 2): scan -> group/global barrier -> combine + head ----------------
// grouped==1: counters = gcnt[g*16], need=15, head over group's 256 elems.
// grouped==0: counter = (unsigned*)out + CNT_IDX, need=240 (R12-proven mode).
__global__ __launch_bounds__(256) void k_scanhead(
    const float* __restrict__ x,  const float* __restrict__ Wx,
    const float* __restrict__ bx, const float* __restrict__ bh,
    const float* __restrict__ Wy, const float* __restrict__ by,
    float* __restrict__ out, float* __restrict__ ws,
    unsigned* __restrict__ gcnt, int grouped)
{
    __shared__ float4 tabs[5200];                // 83200 B -> pins 1 block/CU
    const int blk = blockIdx.x, tid = threadIdx.x;

    const int seg  = (blk < 16) ? 0 : 1;
    const int node = seg ? (blk - 16) >> 4 : 0;
    const int eb   = seg ? (blk - 16) & 15 : blk;   // group id = eb

    unsigned* cnt = grouped ? (gcnt + eb * 16) : ((unsigned*)out + CNT_IDX);
    const unsigned need = grouped ? 15u : (unsigned)NB;

    // pristine poison counter base, read before any arrival (~40us margin)
    const unsigned base = __hip_atomic_load(cnt, __ATOMIC_RELAXED, __HIP_MEMORY_SCOPE_AGENT);

    // ---- table -> LDS (plain cached loads; producer was a separate kernel) ----
    {
        const float4* src = (const float4*)out;  // table in d_out[0..20160)
        for (int i = tid; i < NS * ROWQ; i += 256) tabs[i] = src[i];
    }
    __syncthreads();

    // ---- Phase B: 2-segment speculative scan (R9-validated) ----
    {
        const int b    = eb * 256 + tid;
        const int t0     = seg ? 255 : 0;
        const int nsteps = seg ? 256 : 255;

        float z = seg ? (float)node * DZ14
                      : fminf(fmaxf(__builtin_fmaf(bh[0], S_INVH, S_BIAS), 0.0f), NSM1F);

        auto step1 = [&](float u) {
            float uc = fminf(fmaxf(__builtin_fmaf(u, U_SCALE, U_BIAS), 0.0f), UCMAXF);
            float cf = floorf(uc);
            float xi = __builtin_fmaf(2.0f, uc - cf, -1.0f);
            int   ci = (int)cf;
            float zc  = fminf(fmaxf(z, 0.0f), NSM1F);
            float kzf = fminf(fmaxf(floorf(zc) - 1.0f, 0.0f), NSM4F);
            int   kzi = (int)kzf;
            float ts  = zc - kzf;
            float c0 = ts, c1 = ts - 1.0f, c2 = ts - 2.0f, c3 = ts - 3.0f;
            float n01 = c0 * c1, n23 = c2 * c3;
            float ws0 = c1 * n23 * (-1.0f / 6.0f), ws1 = c0 * n23 * 0.5f;
            float ws2 = n01 * c3 * (-0.5f),        ws3 = n01 * c2 * (1.0f / 6.0f);
            const int base4 = kzi * ROWQ + ci;
            float4 q0 = tabs[base4];
            float4 q1 = tabs[base4 + ROWQ];
            float4 q2 = tabs[base4 + 2 * ROWQ];
            float4 q3 = tabs[base4 + 3 * ROWQ];
            float r0 = __builtin_fmaf(__builtin_fmaf(__builtin_fmaf(q0.w, xi, q0.z), xi, q0.y), xi, q0.x);
            float r1 = __builtin_fmaf(__builtin_fmaf(__builtin_fmaf(q1.w, xi, q1.z), xi, q1.y), xi, q1.x);
            float r2 = __builtin_fmaf(__builtin_fmaf(__builtin_fmaf(q2.w, xi, q2.z), xi, q2.y), xi, q2.x);
            float r3 = __builtin_fmaf(__builtin_fmaf(__builtin_fmaf(q3.w, xi, q3.z), xi, q3.y), xi, q3.x);
            z = __builtin_fmaf(ws0, r0, ws1 * r1) + __builtin_fmaf(ws2, r2, ws3 * r3);
        };

        float cur[8], nxt[8];
#pragma unroll
        for (int i = 0; i < 8; ++i)
            cur[i] = x[(size_t)min(t0 + i, SEQ - 1) * BATCH + b];
        const int full = nsteps >> 3, tail = nsteps & 7;
        for (int c = 0; c < full; ++c) {
            const int nb = t0 + (c + 1) * 8;
#pragma unroll
            for (int i = 0; i < 8; ++i)
                nxt[i] = x[(size_t)min(nb + i, SEQ - 1) * BATCH + b];
#pragma unroll
            for (int i = 0; i < 8; ++i) step1(cur[i]);
#pragma unroll
            for (int i = 0; i < 8; ++i) cur[i] = nxt[i];
        }
        for (int i = 0; i < tail; ++i) step1(cur[i]);

        if (seg == 0) cstore(ws + b, z);
        else          cstore(ws + 4096 + (size_t)node * 4096 + b, z);
    }

    // ---- fence-free barrier (group: 15 arrivals on own line; global: 240) ----
    __syncthreads();
    if (tid == 0) {
        __builtin_amdgcn_s_waitcnt(0);           // drain cstores before arrival
        __hip_atomic_fetch_add(cnt, 1u, __ATOMIC_RELAXED, __HIP_MEMORY_SCOPE_AGENT);
        for (int it = 0; it < 80000; ++it) {     // ~17ms cap: cannot hang
            unsigned v = __hip_atomic_load(cnt, __ATOMIC_RELAXED, __HIP_MEMORY_SCOPE_AGENT);
            if (v - base >= need) break;
            __builtin_amdgcn_s_sleep(8);
        }
    }
    __syncthreads();

    // ---- Phase C: combine + head ----
    {
        const int lane = tid & 63;
        const float C  = 2.8853900817779268f;
        const float L2E = 1.4426950408889634f;
        // grouped: 60 waves cover this group's 256 elems; global: 960 waves/4096
        const int widx   = seg ? (1 + node) : 0;             // 0..14 within group
        const int gw_g   = widx * 4 + (tid >> 6);            // 0..59
        const int gw_all = blk * 4 + (tid >> 6);             // 0..959
        const int e0     = grouped ? (eb * 256 + gw_g) : gw_all;
        const int estep  = grouped ? 60 : (NB * 4);
        const int elim   = grouped ? ((eb + 1) * 256) : BATCH;
        for (int e = e0; e < elim; e += estep) {
            float z255 = cload(ws + e);
            float p = z255 * (1.0f / DZ14);
            int   c = min(max((int)floorf(p) - 1, 0), NNODE - 4);
            float t = p - (float)c;
            float a0 = t, a1 = t - 1.0f, a2 = t - 2.0f, a3 = t - 3.0f;
            float m01 = a0 * a1, m23 = a2 * a3;
            float w0 = a1 * m23 * (-1.0f / 6.0f), w1 = a0 * m23 * 0.5f;
            float w2 = m01 * a3 * (-0.5f),        w3 = m01 * a2 * (1.0f / 6.0f);
            float y0 = cload(ws + 4096 + (size_t)(c + 0) * 4096 + e);
            float y1 = cload(ws + 4096 + (size_t)(c + 1) * 4096 + e);
            float y2 = cload(ws + 4096 + (size_t)(c + 2) * 4096 + e);
            float y3 = cload(ws + 4096 + (size_t)(c + 3) * 4096 + e);
            float zz = __builtin_fmaf(w0, y0, w1 * y1) + __builtin_fmaf(w2, y2, w3 * y3);
            const float s  = __builtin_fmaf(zz, S_H, S_LOc);
            const float u  = x[(size_t)(SEQ - 1) * BATCH + e];
            const float sc = s * C;
            float acc[NOUT];
#pragma unroll
            for (int i = 0; i < NOUT; ++i) acc[i] = 0.0f;
#pragma unroll 4
            for (int k = 0; k < KPL; ++k) {
                const int j = k * 64 + lane;
                float arg = __builtin_fmaf(u, Wx[j] * C, bx[j] * C) + sc;
                float r   = fast_rcp(fast_exp2(arg) + 1.0f);
                float th  = __builtin_fmaf(-2.0f, r, 1.0f);
#pragma unroll
                for (int i = 0; i < NOUT; ++i)
                    acc[i] = __builtin_fmaf(Wy[i * HID + j], th, acc[i]);
            }
#pragma unroll
            for (int i = 0; i < NOUT; ++i) acc[i] = wave_sum(acc[i]) + by[i];
            float m = acc[0];
#pragma unroll
            for (int i = 1; i < NOUT; ++i) m = fmaxf(m, acc[i]);
            float ev[NOUT]; float Z = 0.0f;
#pragma unroll
            for (int i = 0; i < NOUT; ++i) { ev[i] = fast_exp2((acc[i] - m) * L2E); Z += ev[i]; }
            const float rz = fast_rcp(Z);
            if (lane == 0) {
#pragma unroll
                for (int i = 0; i < NOUT; ++i) out[(size_t)e * NOUT + i] = ev[i] * rz;
            }
        }
    }
}

// ==================== fallbacks (validated R0/R9) ====================
__device__ __forceinline__ float combine_eval(float z255, int nn, float dz,
                                              const float* baseA, const float* baseB,
                                              int split, int b) {
    float p = z255 / dz;
    int   c = min(max((int)floorf(p) - 1, 0), nn - 4);
    float t = p - (float)c;
    float a0 = t, a1 = t - 1.0f, a2 = t - 2.0f, a3 = t - 3.0f;
    float m01 = a0 * a1, m23 = a2 * a3;
    float w0 = a1 * m23 * (-1.0f / 6.0f), w1 = a0 * m23 * 0.5f;
    float w2 = m01 * a3 * (-0.5f),        w3 = m01 * a2 * (1.0f / 6.0f);
    float y[4];
#pragma unroll
    for (int i = 0; i < 4; ++i) {
        int n = c + i;
        const float* ptr = (n < split) ? (baseA + (size_t)n * 4096)
                                       : (baseB + (size_t)(n - split) * 4096);
        y[i] = ptr[b];
    }
    return __builtin_fmaf(w0, y[0], w1 * y[1]) + __builtin_fmaf(w2, y[2], w3 * y[3]);
}

__global__ __launch_bounds__(256) void k_scan_seg(const float* __restrict__ x,
                                                  const float* __restrict__ bh,
                                                  const float* __restrict__ tab_g,
                                                  float* __restrict__ z255,
                                                  float* __restrict__ baseA,
                                                  float* __restrict__ baseB,
                                                  int split, float dz) {
    __shared__ float4 tabs[5200];
    {
        const float4* src = (const float4*)tab_g;
        for (int i = threadIdx.x; i < NS * ROWQ; i += 256) tabs[i] = src[i];
    }
    __syncthreads();
    const int blk = blockIdx.x;
    const int seg  = (blk < 16) ? 0 : 1;
    const int node = seg ? (blk - 16) >> 4 : 0;
    const int eb   = seg ? (blk - 16) & 15 : blk;
    const int b    = eb * 256 + threadIdx.x;
    const int t0     = seg ? 255 : 0;
    const int nsteps = seg ? 256 : 255;
    float z = seg ? (float)node * dz
                  : fminf(fmaxf(__builtin_fmaf(bh[0], S_INVH, S_BIAS), 0.0f), NSM1F);
    auto step1 = [&](float u) {
        float uc = fminf(fmaxf(__builtin_fmaf(u, U_SCALE, U_BIAS), 0.0f), UCMAXF);
        float cf = floorf(uc);
        float xi = __builtin_fmaf(2.0f, uc - cf, -1.0f);
        int   ci = (int)cf;
        float zc  = fminf(fmaxf(z, 0.0f), NSM1F);
        float kzf = fminf(fmaxf(floorf(zc) - 1.0f, 0.0f), NSM4F);
        int   kzi = (int)kzf;
        float ts  = zc - kzf;
        float c0 = ts, c1 = ts - 1.0f, c2 = ts - 2.0f, c3 = ts - 3.0f;
        float n01 = c0 * c1, n23 = c2 * c3;
        float ws0 = c1 * n23 * (-1.0f / 6.0f), ws1 = c0 * n23 * 0.5f;
        float ws2 = n01 * c3 * (-0.5f),        ws3 = n01 * c2 * (1.0f / 6.0f);
        const int base = kzi * ROWQ + ci;
        float4 q0 = tabs[base];
        float4 q1 = tabs[base + ROWQ];
        float4 q2 = tabs[base + 2 * ROWQ];
        float4 q3 = tabs[base + 3 * ROWQ];
        float r0 = __builtin_fmaf(__builtin_fmaf(__builtin_fmaf(q0.w, xi, q0.z), xi, q0.y), xi, q0.x);
        float r1 = __builtin_fmaf(__builtin_fmaf(__builtin_fmaf(q1.w, xi, q1.z), xi, q1.y), xi, q1.x);
        float r2 = __builtin_fmaf(__builtin_fmaf(__builtin_fmaf(q2.w, xi, q2.z), xi, q2.y), xi, q2.x);
        float r3 = __builtin_fmaf(__builtin_fmaf(__builtin_fmaf(q3.w, xi, q3.z), xi, q3.y), xi, q3.x);
        z = __builtin_fmaf(ws0, r0, ws1 * r1) + __builtin_fmaf(ws2, r2, ws3 * r3);
    };
    float cur[8], nxt[8];
#pragma unroll
    for (int i = 0; i < 8; ++i)
        cur[i] = x[(size_t)min(t0 + i, SEQ - 1) * BATCH + b];
    const int full = nsteps >> 3, tail = nsteps & 7;
    for (int c = 0; c < full; ++c) {
        const int nb = t0 + (c + 1) * 8;
#pragma unroll
        for (int i = 0; i < 8; ++i)
            nxt[i] = x[(size_t)min(nb + i, SEQ - 1) * BATCH + b];
#pragma unroll
        for (int i = 0; i < 8; ++i) step1(cur[i]);
#pragma unroll
        for (int i = 0; i < 8; ++i) cur[i] = nxt[i];
    }
    for (int i = 0; i < tail; ++i) step1(cur[i]);
    if (seg == 0) z255[b] = z;
    else {
        float* p = (node < split) ? (baseA + (size_t)node * 4096)
                                  : (baseB + (size_t)(node - split) * 4096);
        p[b] = z;
    }
}

__global__ __launch_bounds__(256) void k_combine(const float* __restrict__ baseA,
                                                 const float* __restrict__ baseB,
                                                 int split, int nn, float dz,
                                                 float* __restrict__ zs) {
    const int b = blockIdx.x * 256 + threadIdx.x;
    float zz = combine_eval(zs[b], nn, dz, baseA, baseB, split, b);
    zs[b] = __builtin_fmaf(zz, S_H, S_LOc);
}

__global__ __launch_bounds__(256) void rnn_scan_exact(
    const float* __restrict__ x,  const float* __restrict__ Wx,
    const float* __restrict__ bx, const float* __restrict__ Wh,
    const float* __restrict__ bh, float* __restrict__ s_out)
{
    const int lane = threadIdx.x & 63;
    const int wave = threadIdx.x >> 6;
    const int b    = blockIdx.x * 4 + wave;
    const float C = 2.8853900817779268f;
    float wxs[KPL], bxs[KPL], whn[KPL];
    float swh = 0.0f;
#pragma unroll
    for (int k = 0; k < KPL; ++k) {
        const int j = k * 64 + lane;
        const float w = Wh[j];
        wxs[k] = Wx[j] * C; bxs[k] = bx[j] * C; whn[k] = -2.0f * w; swh += w;
    }
    swh = wave_sum(swh);
    const float bh0 = bh[0];
    const float K0  = bh0 + swh;
    float s = bh0, u = x[b];
    for (int t = 0; t < SEQ - 1; ++t) {
        float u_next = x[(size_t)(t + 1) * BATCH + b];
        const float sc = s * C;
        float p = 0.0f;
#pragma unroll
        for (int k = 0; k < KPL; ++k) {
            float arg = __builtin_fmaf(u, wxs[k], bxs[k]) + sc;
            float r   = fast_rcp(fast_exp2(arg) + 1.0f);
            p = __builtin_fmaf(whn[k], r, p);
        }
        s = K0 + wave_sum(p);
        u = u_next;
    }
    if (lane == 0) s_out[b] = s;
}

__global__ __launch_bounds__(256) void rnn_head_exact(
    const float* __restrict__ x,  const float* __restrict__ Wx,
    const float* __restrict__ bx, const float* __restrict__ Wy,
    const float* __restrict__ by, const float* __restrict__ s_in,
    float* __restrict__ out)
{
    const int lane = threadIdx.x & 63;
    const int wave = threadIdx.x >> 6;
    const int b    = blockIdx.x * 4 + wave;
    const float C  = 2.8853900817779268f;
    const float s  = s_in[b];
    const float u  = x[(size_t)(SEQ - 1) * BATCH + b];
    const float sc = s * C;
    float acc[NOUT];
#pragma unroll
    for (int i = 0; i < NOUT; ++i) acc[i] = 0.0f;
#pragma unroll 4
    for (int k = 0; k < KPL; ++k) {
        const int j = k * 64 + lane;
        float arg = __builtin_fmaf(u, Wx[j] * C, bx[j] * C) + sc;
        float r   = fast_rcp(fast_exp2(arg) + 1.0f);
        float th  = __builtin_fmaf(-2.0f, r, 1.0f);
#pragma unroll
        for (int i = 0; i < NOUT; ++i)
            acc[i] = __builtin_fmaf(Wy[i * HID + j], th, acc[i]);
    }
#pragma unroll
    for (int i = 0; i < NOUT; ++i) acc[i] = wave_sum(acc[i]) + by[i];
    float m = acc[0];
#pragma unroll
    for (int i = 1; i < NOUT; ++i) m = fmaxf(m, acc[i]);
    const float L2E = 1.4426950408889634f;
    float ev[NOUT]; float Z = 0.0f;
#pragma unroll
    for (int i = 0; i < NOUT; ++i) { ev[i] = fast_exp2((acc[i] - m) * L2E); Z += ev[i]; }
    const float rz = fast_rcp(Z);
    if (lane == 0) {
#pragma unroll
        for (int i = 0; i < NOUT; ++i) out[(size_t)b * NOUT + i] = ev[i] * rz;
    }
}

extern "C" void kernel_launch(void* const* d_in, const int* in_sizes, int n_in,
                              void* d_out, int out_size, void* d_ws, size_t ws_size,
                              hipStream_t stream)
{
    const float* x  = (const float*)d_in[0];
    const float* Wx = (const float*)d_in[1];
    const float* bx = (const float*)d_in[2];
    const float* Wh = (const float*)d_in[3];
    const float* bh = (const float*)d_in[4];
    const float* Wy = (const float*)d_in[5];
    const float* by = (const float*)d_in[6];
    float* out = (float*)d_out;
    float* wf  = (float*)d_ws;

    if (ws_size >= (size_t)WSG_FLOATS * sizeof(float)) {
        // R13: group-barrier mode (16 parallel 15-arrival barriers in ws tail)
        k_coef<<<NS, 256, 0, stream>>>(Wx, bx, Wh, bh, out);
        k_scanhead<<<NB, 256, 0, stream>>>(x, Wx, bx, bh, Wy, by, out, wf,
                                           (unsigned*)(wf + WSA_FLOATS), 1);
    } else if (ws_size >= (size_t)WSA_FLOATS * sizeof(float)) {
        // R12-proven global-barrier mode (counter in d_out tail)
        k_coef<<<NS, 256, 0, stream>>>(Wx, bx, Wh, bh, out);
        k_scanhead<<<NB, 256, 0, stream>>>(x, Wx, bx, bh, Wy, by, out, wf,
                                           (unsigned*)out, 0);
    } else if (ws_size >= (size_t)WSB_FLOATS * sizeof(float)) {
        // Tier B fallback (R9)
        k_coef<<<NS, 256, 0, stream>>>(Wx, bx, Wh, bh, out);
        k_scan_seg<<<16 + 9 * 16, 256, 0, stream>>>(x, bh, out, wf,
                                                    out + TABLE_FLOATS, wf + 4096, 5, DZ9);
        k_combine<<<16, 256, 0, stream>>>(out + TABLE_FLOATS, wf + 4096, 5, 9, DZ9, wf);
        rnn_head_exact<<<BATCH / 4, 256, 0, stream>>>(x, Wx, bx, Wy, by, wf, out);
    } else {
        rnn_scan_exact<<<BATCH / 4, 256, 0, stream>>>(x, Wx, bx, Wh, bh, wf);
        rnn_head_exact<<<BATCH / 4, 256, 0, stream>>>(x, Wx, bx, Wy, by, wf, out);
    }
}

// Round 14
// 153.162 us; speedup vs baseline: 1.3321x; 1.0014x over previous
//
#include <hip/hip_runtime.h>
#include <math.h>

// VanillaRNN, Wh is (1,H) => scalar recurrence per batch element:
//   s_{t+1} = G(u_t, s_t),  G(u,s) = bh + sum_j wh_j*tanh(wx_j*u + bx_j + s)
// R14: R9's proven 3-node pipeline (coef -> 2-segment speculative scan ->
// combine+head; kernel boundaries as barriers — measured cheapest at ~8us/node
// vs ~20-30us for in-kernel grid barriers, R10-R13). Scan is per-step
// CHAIN-LATENCY bound (R5 1-wave 653 cyc/step vs R6 4-wave 345/round =
// superlinear => latency, not DS throughput). This round shortens the chain:
//  - QUADRATIC-in-s on NS=1120 rows (h=0.0179): 3x ds_read_b128 per step
//    (was 4), shorter weight tree. err ~0.064 h^3|G'''| ~ 1e-6/step -> absmax
//    ~5e-4 (threshold 1.59e-2).
//  - Row stride 8 float4s (no pad; x32 floats => shift-only addressing) with
//    ADD-SWIZZLE cell' = (ci+row)&7 -> bank 4*((ci+kzi)&7) spread by kzi
//    (avoids R4's u-concentration pathology without the pad multiply).
//  - Table 143KB LDS (1 block/CU). k_coef: 1120 blocks (~9us).
// Combine: 14-node piecewise cubic (R9-validated, absmax floor 2.44e-4).

#define SEQ   512
#define BATCH 4096
#define HID   2048
#define NOUT  10
#define KPL   32
#define NS    1120          // s-grid rows over [-10,10]
#define NB    240           // 16 seg0 + 14 nodes x 16 seg1
#define NNODE 14

#define S_LOc   (-10.0f)
#define S_H     (20.0f / 1119.0f)
#define S_INVH  (1119.0f / 20.0f)
#define S_BIAS  (10.0f * S_INVH)    // 559.5
#define NSM1F   1119.0f
#define NSM3F   1117.0f             // max quadratic stencil base
#define U_SCALE (8.0f / 14.0f)
#define U_BIAS  4.0f
#define UCMAXF  7.99951f
#define DZ14    (1119.0f / 13.0f)   // combine node spacing (z-units)

#define TABLE_FLOATS (NS * 8 * 4)        // 35840 floats in d_out (<=40960)
#define WSA_FLOATS   (4096 + 14 * 4096)  // z255 + 14 node bufs (R9-proven)

__device__ __forceinline__ float fast_exp2(float v) { return __builtin_amdgcn_exp2f(v); }
__device__ __forceinline__ float fast_rcp(float v)  { return __builtin_amdgcn_rcpf(v); }
__device__ __forceinline__ float fast_tanh(float a) {
    const float C = 2.8853900817779268f;  // 2*log2(e)
    return __builtin_fmaf(-2.0f, fast_rcp(fast_exp2(C * a) + 1.0f), 1.0f);
}
__device__ __forceinline__ float wave_sum(float v) {
#pragma unroll
    for (int m = 1; m < 64; m <<= 1) v += __shfl_xor(v, m, 64);
    return v;
}

// ---------------- K1: coefficient table (1120 s-rows x 8 u-cells, swizzled) ----------------
__global__ __launch_bounds__(256) void k_coef(const float* __restrict__ Wx, const float* __restrict__ bx,
                                              const float* __restrict__ Wh, const float* __restrict__ bh,
                                              float* __restrict__ tab_g) {
    __shared__ float red[256];
    __shared__ float Gn[32];
    const int k    = blockIdx.x;                 // s-row
    const int node = threadIdx.x & 31, jc = threadIdx.x >> 5;
    const int cell = node >> 2, nn = node & 3;   // 8 u-cells x 4 Chebyshev nodes
    const float sn = S_LOc + (float)k * S_H;
    const float xi_n = (nn == 0) ? 0.923879533f : (nn == 1) ? 0.382683432f
                     : (nn == 2) ? -0.382683432f : -0.923879533f;
    const float un = (-7.0f + ((float)cell + 0.5f) * 1.75f) + 0.875f * xi_n;
    float p = 0.0f;
    const int j0 = jc * 256;
#pragma unroll 4
    for (int j = j0; j < j0 + 256; ++j)
        p += Wh[j] * fast_tanh(__builtin_fmaf(Wx[j], un, bx[j] + sn));
    red[threadIdx.x] = p;
    __syncthreads();
    if (threadIdx.x < 32) {
        float V = bh[0];
#pragma unroll
        for (int c = 0; c < 8; ++c) V += red[threadIdx.x + 32 * c];
        Gn[threadIdx.x] = __builtin_fmaf(V, S_INVH, S_BIAS);   // normalized next-z
    }
    __syncthreads();
    float4* wq = (float4*)tab_g;
    if (threadIdx.x < 8) {
        const int c = threadIdx.x;
        float G0 = Gn[4*c+0], G1 = Gn[4*c+1], G2 = Gn[4*c+2], G3 = Gn[4*c+3];
        float d03 = G0 - G3, d12 = G1 - G2;
        float a0 = 0.25f * (G0 + G1 + G2 + G3);
        float a1 = 0.5f * (0.923879533f * d03 + 0.382683432f * d12);
        float a2 = 0.5f * 0.707106781f * (G0 - G1 - G2 + G3);
        float a3 = 0.5f * (0.382683432f * d03 - 0.923879533f * d12);
        // T-basis -> monomial; swizzled cell position (c + k) & 7
        wq[k * 8 + ((c + k) & 7)] =
            make_float4(a0 - a2, a1 - 3.0f * a3, 2.0f * a2, 4.0f * a3);
    }
}

// ---------------- K2: 2-segment speculative scan, quadratic-s ----------------
__global__ __launch_bounds__(256) void k_scan_seg(const float* __restrict__ x,
                                                  const float* __restrict__ bh,
                                                  const float* __restrict__ tab_g,
                                                  float* __restrict__ ws) {
    __shared__ float4 tabs[NS * 8];              // 143360 B -> 1 block/CU
    {
        const float4* src = (const float4*)tab_g;
        for (int i = threadIdx.x; i < NS * 8; i += 256) tabs[i] = src[i];
    }
    __syncthreads();
    const int blk = blockIdx.x;
    const int seg  = (blk < 16) ? 0 : 1;
    const int node = seg ? (blk - 16) >> 4 : 0;
    const int eb   = seg ? (blk - 16) & 15 : blk;
    const int b    = eb * 256 + threadIdx.x;
    const int t0     = seg ? 255 : 0;
    const int nsteps = seg ? 256 : 255;

    float z = seg ? (float)node * DZ14
                  : fminf(fmaxf(__builtin_fmaf(bh[0], S_INVH, S_BIAS), 0.0f), NSM1F);

    auto step1 = [&](float u) {
        // ---- u side (independent of s) ----
        float uc = fminf(fmaxf(__builtin_fmaf(u, U_SCALE, U_BIAS), 0.0f), UCMAXF);
        float cf = floorf(uc);
        float xi = __builtin_fmaf(2.0f, uc - cf, -1.0f);
        int   ci = (int)cf;
        // ---- s side: the serial chain (short) ----
        float zc  = fminf(fmaxf(z, 0.0f), NSM1F);
        float kzf = fminf(fmaxf(floorf(zc - 0.5f), 0.0f), NSM3F);
        int   kzi = (int)kzf;
        float ts  = zc - kzf;                    // in [0.5,1.5] interior
        // quadratic Lagrange weights at nodes {0,1,2}
        float w0 = 0.5f * (ts - 1.0f) * (ts - 2.0f);
        float w1 = ts * (2.0f - ts);
        float w2 = 0.5f * ts * (ts - 1.0f);
        const int cs = ci + kzi;
        float4 q0 = tabs[(kzi    ) * 8 + ( cs      & 7)];
        float4 q1 = tabs[(kzi + 1) * 8 + ((cs + 1) & 7)];
        float4 q2 = tabs[(kzi + 2) * 8 + ((cs + 2) & 7)];
        float r0 = __builtin_fmaf(__builtin_fmaf(__builtin_fmaf(q0.w, xi, q0.z), xi, q0.y), xi, q0.x);
        float r1 = __builtin_fmaf(__builtin_fmaf(__builtin_fmaf(q1.w, xi, q1.z), xi, q1.y), xi, q1.x);
        float r2 = __builtin_fmaf(__builtin_fmaf(__builtin_fmaf(q2.w, xi, q2.z), xi, q2.y), xi, q2.x);
        z = __builtin_fmaf(w0, r0, __builtin_fmaf(w1, r1, w2 * r2));
    };

    float cur[8], nxt[8];
#pragma unroll
    for (int i = 0; i < 8; ++i)
        cur[i] = x[(size_t)min(t0 + i, SEQ - 1) * BATCH + b];
    const int full = nsteps >> 3, tail = nsteps & 7;
    for (int c = 0; c < full; ++c) {
        const int nb = t0 + (c + 1) * 8;
#pragma unroll
        for (int i = 0; i < 8; ++i)
            nxt[i] = x[(size_t)min(nb + i, SEQ - 1) * BATCH + b];
#pragma unroll
        for (int i = 0; i < 8; ++i) step1(cur[i]);
#pragma unroll
        for (int i = 0; i < 8; ++i) cur[i] = nxt[i];
    }
    for (int i = 0; i < tail; ++i) step1(cur[i]);    // wave-uniform tail (<=7)

    if (seg == 0) ws[b] = z;
    else          ws[4096 + (size_t)node * 4096 + b] = z;
}

// ---------------- K3: fused combine (14-node piecewise cubic) + head ----------------
__global__ __launch_bounds__(256) void head_combine_A(
    const float* __restrict__ x,  const float* __restrict__ Wx,
    const float* __restrict__ bx, const float* __restrict__ Wy,
    const float* __restrict__ by, const float* __restrict__ ws,
    float* __restrict__ out)
{
    const int lane = threadIdx.x & 63;
    const int wave = threadIdx.x >> 6;
    const int b    = blockIdx.x * 4 + wave;

    float p = ws[b] * (1.0f / DZ14);
    int   c = min(max((int)floorf(p) - 1, 0), NNODE - 4);
    float t = p - (float)c;
    float a0 = t, a1 = t - 1.0f, a2 = t - 2.0f, a3 = t - 3.0f;
    float m01 = a0 * a1, m23 = a2 * a3;
    float w0 = a1 * m23 * (-1.0f / 6.0f), w1 = a0 * m23 * 0.5f;
    float w2 = m01 * a3 * (-0.5f),        w3 = m01 * a2 * (1.0f / 6.0f);
    float y0 = ws[4096 + (size_t)(c + 0) * 4096 + b];
    float y1 = ws[4096 + (size_t)(c + 1) * 4096 + b];
    float y2 = ws[4096 + (size_t)(c + 2) * 4096 + b];
    float y3 = ws[4096 + (size_t)(c + 3) * 4096 + b];
    float zz = __builtin_fmaf(w0, y0, w1 * y1) + __builtin_fmaf(w2, y2, w3 * y3);
    const float s = __builtin_fmaf(zz, S_H, S_LOc);

    const float C  = 2.8853900817779268f;
    const float u  = x[(size_t)(SEQ - 1) * BATCH + b];
    const float sc = s * C;
    float acc[NOUT];
#pragma unroll
    for (int i = 0; i < NOUT; ++i) acc[i] = 0.0f;
#pragma unroll 4
    for (int k = 0; k < KPL; ++k) {
        const int j = k * 64 + lane;
        float arg = __builtin_fmaf(u, Wx[j] * C, bx[j] * C) + sc;
        float r   = fast_rcp(fast_exp2(arg) + 1.0f);
        float th  = __builtin_fmaf(-2.0f, r, 1.0f);
#pragma unroll
        for (int i = 0; i < NOUT; ++i)
            acc[i] = __builtin_fmaf(Wy[i * HID + j], th, acc[i]);
    }
#pragma unroll
    for (int i = 0; i < NOUT; ++i) acc[i] = wave_sum(acc[i]) + by[i];
    float m = acc[0];
#pragma unroll
    for (int i = 1; i < NOUT; ++i) m = fmaxf(m, acc[i]);
    const float L2E = 1.4426950408889634f;
    float ev[NOUT]; float Z = 0.0f;
#pragma unroll
    for (int i = 0; i < NOUT; ++i) { ev[i] = fast_exp2((acc[i] - m) * L2E); Z += ev[i]; }
    const float rz = fast_rcp(Z);
    if (lane == 0) {
#pragma unroll
        for (int i = 0; i < NOUT; ++i) out[(size_t)b * NOUT + i] = ev[i] * rz;
    }
}

// ---------------- exact fallback scan + head (validated R0) ----------------
__global__ __launch_bounds__(256) void rnn_scan_exact(
    const float* __restrict__ x,  const float* __restrict__ Wx,
    const float* __restrict__ bx, const float* __restrict__ Wh,
    const float* __restrict__ bh, float* __restrict__ s_out)
{
    const int lane = threadIdx.x & 63;
    const int wave = threadIdx.x >> 6;
    const int b    = blockIdx.x * 4 + wave;
    const float C = 2.8853900817779268f;
    float wxs[KPL], bxs[KPL], whn[KPL];
    float swh = 0.0f;
#pragma unroll
    for (int k = 0; k < KPL; ++k) {
        const int j = k * 64 + lane;
        const float w = Wh[j];
        wxs[k] = Wx[j] * C; bxs[k] = bx[j] * C; whn[k] = -2.0f * w; swh += w;
    }
    swh = wave_sum(swh);
    const float bh0 = bh[0];
    const float K0  = bh0 + swh;
    float s = bh0, u = x[b];
    for (int t = 0; t < SEQ - 1; ++t) {
        float u_next = x[(size_t)(t + 1) * BATCH + b];
        const float sc = s * C;
        float p = 0.0f;
#pragma unroll
        for (int k = 0; k < KPL; ++k) {
            float arg = __builtin_fmaf(u, wxs[k], bxs[k]) + sc;
            float r   = fast_rcp(fast_exp2(arg) + 1.0f);
            p = __builtin_fmaf(whn[k], r, p);
        }
        s = K0 + wave_sum(p);
        u = u_next;
    }
    if (lane == 0) s_out[b] = s;
}

__global__ __launch_bounds__(256) void rnn_head_exact(
    const float* __restrict__ x,  const float* __restrict__ Wx,
    const float* __restrict__ bx, const float* __restrict__ Wy,
    const float* __restrict__ by, const float* __restrict__ s_in,
    float* __restrict__ out)
{
    const int lane = threadIdx.x & 63;
    const int wave = threadIdx.x >> 6;
    const int b    = blockIdx.x * 4 + wave;
    const float C  = 2.8853900817779268f;
    const float s  = s_in[b];
    const float u  = x[(size_t)(SEQ - 1) * BATCH + b];
    const float sc = s * C;
    float acc[NOUT];
#pragma unroll
    for (int i = 0; i < NOUT; ++i) acc[i] = 0.0f;
#pragma unroll 4
    for (int k = 0; k < KPL; ++k) {
        const int j = k * 64 + lane;
        float arg = __builtin_fmaf(u, Wx[j] * C, bx[j] * C) + sc;
        float r   = fast_rcp(fast_exp2(arg) + 1.0f);
        float th  = __builtin_fmaf(-2.0f, r, 1.0f);
#pragma unroll
        for (int i = 0; i < NOUT; ++i)
            acc[i] = __builtin_fmaf(Wy[i * HID + j], th, acc[i]);
    }
#pragma unroll
    for (int i = 0; i < NOUT; ++i) acc[i] = wave_sum(acc[i]) + by[i];
    float m = acc[0];
#pragma unroll
    for (int i = 1; i < NOUT; ++i) m = fmaxf(m, acc[i]);
    const float L2E = 1.4426950408889634f;
    float ev[NOUT]; float Z = 0.0f;
#pragma unroll
    for (int i = 0; i < NOUT; ++i) { ev[i] = fast_exp2((acc[i] - m) * L2E); Z += ev[i]; }
    const float rz = fast_rcp(Z);
    if (lane == 0) {
#pragma unroll
        for (int i = 0; i < NOUT; ++i) out[(size_t)b * NOUT + i] = ev[i] * rz;
    }
}

extern "C" void kernel_launch(void* const* d_in, const int* in_sizes, int n_in,
                              void* d_out, int out_size, void* d_ws, size_t ws_size,
                              hipStream_t stream)
{
    const float* x  = (const float*)d_in[0];
    const float* Wx = (const float*)d_in[1];
    const float* bx = (const float*)d_in[2];
    const float* Wh = (const float*)d_in[3];
    const float* bh = (const float*)d_in[4];
    const float* Wy = (const float*)d_in[5];
    const float* by = (const float*)d_in[6];
    float* out = (float*)d_out;
    float* wf  = (float*)d_ws;

    if (ws_size >= (size_t)WSA_FLOATS * sizeof(float)) {
        // R14: 3 nodes — coef (1120 rows), quadratic-s scan, combine+head
        k_coef<<<NS, 256, 0, stream>>>(Wx, bx, Wh, bh, out);
        k_scan_seg<<<NB, 256, 0, stream>>>(x, bh, out, wf);
        head_combine_A<<<BATCH / 4, 256, 0, stream>>>(x, Wx, bx, Wy, by, wf, out);
    } else {
        rnn_scan_exact<<<BATCH / 4, 256, 0, stream>>>(x, Wx, bx, Wh, bh, wf);
        rnn_head_exact<<<BATCH / 4, 256, 0, stream>>>(x, Wx, bx, Wy, by, wf, out);
    }
}